// Round 1
// baseline (3762.096 us; speedup 1.0000x reference)
//
#include <hip/hip_runtime.h>
#include <math.h>

#define N_IMG 32
#define P2304 2304
#define CIN 512
#define CMID 256
#define C2 128
#define LEV 128

// ---------------- wave/block reduction helpers (wave = 64) ----------------
__device__ __forceinline__ float wredSum(float v){
#pragma unroll
  for (int o = 32; o > 0; o >>= 1) v += __shfl_down(v, o, 64);
  return v;
}
__device__ __forceinline__ float wredMax(float v){
#pragma unroll
  for (int o = 32; o > 0; o >>= 1) v = fmaxf(v, __shfl_down(v, o, 64));
  return v;
}
__device__ __forceinline__ float wredMin(float v){
#pragma unroll
  for (int o = 32; o > 0; o >>= 1) v = fminf(v, __shfl_down(v, o, 64));
  return v;
}

// ---------------- weight reorder kernels ----------------
// wg[r][ci][co] = conv1_w[co][ci][r]   (r = kh*3+kw)
__global__ void reorder_w1_kernel(const float* __restrict__ w1, float* __restrict__ wg){
  int idx = blockIdx.x * 256 + threadIdx.x;
  if (idx >= 9 * CIN * CMID) return;
  int co = idx & 255;
  int ci = (idx >> 8) & 511;
  int r  = idx >> 17;
  wg[idx] = w1[co * (CIN * 9) + ci * 9 + r];
}

// w2t[c][o] = conv2_w[o][c]
__global__ void transpose_w2_kernel(const float* __restrict__ w2, float* __restrict__ w2t){
  int idx = blockIdx.x * 256 + threadIdx.x;
  if (idx >= C2 * CMID) return;
  int o = idx & 127;
  int c = idx >> 7;
  w2t[idx] = w2[o * CMID + c];
}

// ---------------- conv1 (3x3 SAME, 512->256) + bn1 + leaky ----------------
// implicit GEMM: M=256(co), N=2304(p), K=4608 (k = r*512+ci). 128x128 tile,
// 8x8 per thread (split 4+4 so LDS fragment reads are 2-way -> conflict-free).
__global__ __launch_bounds__(256) void conv1_kernel(
    const float* __restrict__ x, const float* __restrict__ wg,
    const float* __restrict__ g1, const float* __restrict__ b1,
    const float* __restrict__ m1, const float* __restrict__ v1,
    float* __restrict__ y)
{
  __shared__ float Wt[16][132];
  __shared__ float Xt[16][132];
  int t = threadIdx.x;
  int pt = blockIdx.x % 18;
  int cot = (blockIdx.x / 18) & 1;
  int n = blockIdx.x / 36;
  int pbase = pt * 128, cobase = cot * 128;
  int tx = t & 15, ty = t >> 4;
  const float* xn = x + n * CIN * P2304;

  float acc[8][8];
#pragma unroll
  for (int a = 0; a < 8; a++)
#pragma unroll
    for (int b = 0; b < 8; b++) acc[a][b] = 0.f;

  for (int kt = 0; kt < 288; ++kt){
    int r = kt >> 5;              // tap 0..8 (uniform within 16-chunk: 512%16==0)
    int ci0 = (kt & 31) << 4;
    int dh = r / 3 - 1, dw = r - (r / 3) * 3 - 1;
    __syncthreads();
    // stage W: 16x128 floats as 512 float4 (coalesced, wg pre-reordered)
#pragma unroll
    for (int i = 0; i < 2; i++){
      int v4 = t + 256 * i;
      int kk = v4 >> 5;
      int c4 = (v4 & 31) << 2;
      *(float4*)&Wt[kk][c4] =
        *(const float4*)(wg + (((r << 9) + ci0 + kk) << 8) + cobase + c4);
    }
    // stage X: 16x128 scalars with zero padding at image border
#pragma unroll
    for (int i = 0; i < 8; i++){
      int vs = t + 256 * i;
      int kk = vs >> 7;
      int pp = vs & 127;
      int p = pbase + pp;
      int ph = p / 48;
      int hh = ph + dh;
      int ww = p - ph * 48 + dw;
      float val = 0.f;
      if ((unsigned)hh < 48u && (unsigned)ww < 48u)
        val = xn[(ci0 + kk) * P2304 + hh * 48 + ww];
      Xt[kk][pp] = val;
    }
    __syncthreads();
#pragma unroll
    for (int kk = 0; kk < 16; kk++){
      float4 xv0 = *(float4*)&Xt[kk][tx * 4];
      float4 xv1 = *(float4*)&Xt[kk][tx * 4 + 64];
      float4 wv0 = *(float4*)&Wt[kk][ty * 4];
      float4 wv1 = *(float4*)&Wt[kk][ty * 4 + 64];
      float xf[8] = {xv0.x, xv0.y, xv0.z, xv0.w, xv1.x, xv1.y, xv1.z, xv1.w};
      float wf[8] = {wv0.x, wv0.y, wv0.z, wv0.w, wv1.x, wv1.y, wv1.z, wv1.w};
#pragma unroll
      for (int a = 0; a < 8; a++)
#pragma unroll
        for (int b = 0; b < 8; b++)
          acc[a][b] += wf[a] * xf[b];
    }
  }
  // epilogue: bn1 + leaky relu, float4 stores
#pragma unroll
  for (int a = 0; a < 8; a++){
    int co = cobase + ty * 4 + (a & 3) + ((a >> 2) << 6);
    float sc = g1[co] * (1.0f / sqrtf(v1[co] + 1e-5f));
    float mu = m1[co], bc = b1[co];
    float o[8];
#pragma unroll
    for (int b = 0; b < 8; b++){
      float val = (acc[a][b] - mu) * sc + bc;
      o[b] = val > 0.f ? val : 0.01f * val;
    }
    float* dst = y + (n * CMID + co) * P2304 + pbase + tx * 4;
    *(float4*)dst        = make_float4(o[0], o[1], o[2], o[3]);
    *(float4*)(dst + 64) = make_float4(o[4], o[5], o[6], o[7]);
  }
}

// ---------------- conv2 (1x1, 256->128) ----------------
__global__ __launch_bounds__(256) void conv2_kernel(
    const float* __restrict__ y, const float* __restrict__ w2t, float* __restrict__ x2)
{
  __shared__ float Wt[16][132];
  __shared__ float Xt[16][132];
  int t = threadIdx.x;
  int pt = blockIdx.x % 18;
  int n = blockIdx.x / 18;
  int pbase = pt * 128;
  int tx = t & 15, ty = t >> 4;

  float acc[8][8];
#pragma unroll
  for (int a = 0; a < 8; a++)
#pragma unroll
    for (int b = 0; b < 8; b++) acc[a][b] = 0.f;

  for (int kt = 0; kt < 16; ++kt){
    int c0 = kt << 4;
    __syncthreads();
#pragma unroll
    for (int i = 0; i < 2; i++){
      int v4 = t + 256 * i;
      int kk = v4 >> 5;
      int c4 = (v4 & 31) << 2;
      *(float4*)&Wt[kk][c4] = *(const float4*)(w2t + (c0 + kk) * 128 + c4);
    }
#pragma unroll
    for (int i = 0; i < 2; i++){
      int v4 = t + 256 * i;
      int kk = v4 >> 5;
      int p4 = (v4 & 31) << 2;
      *(float4*)&Xt[kk][p4] =
        *(const float4*)(y + (n * CMID + c0 + kk) * P2304 + pbase + p4);
    }
    __syncthreads();
#pragma unroll
    for (int kk = 0; kk < 16; kk++){
      float4 xv0 = *(float4*)&Xt[kk][tx * 4];
      float4 xv1 = *(float4*)&Xt[kk][tx * 4 + 64];
      float4 wv0 = *(float4*)&Wt[kk][ty * 4];
      float4 wv1 = *(float4*)&Wt[kk][ty * 4 + 64];
      float xf[8] = {xv0.x, xv0.y, xv0.z, xv0.w, xv1.x, xv1.y, xv1.z, xv1.w};
      float wf[8] = {wv0.x, wv0.y, wv0.z, wv0.w, wv1.x, wv1.y, wv1.z, wv1.w};
#pragma unroll
      for (int a = 0; a < 8; a++)
#pragma unroll
        for (int b = 0; b < 8; b++)
          acc[a][b] += wf[a] * xf[b];
    }
  }
#pragma unroll
  for (int a = 0; a < 8; a++){
    int oo = ty * 4 + (a & 3) + ((a >> 2) << 6);
    float* dst = x2 + (n * C2 + oo) * P2304 + pbase + tx * 4;
    *(float4*)dst        = make_float4(acc[a][0], acc[a][1], acc[a][2], acc[a][3]);
    *(float4*)(dst + 64) = make_float4(acc[a][4], acc[a][5], acc[a][6], acc[a][7]);
  }
}

// ---------------- x_ave (mean over 2304 positions per (n,c)) ----------------
__global__ void xave_kernel(const float* __restrict__ x2, float* __restrict__ xave){
  __shared__ float red[4];
  int nc = blockIdx.x, t = threadIdx.x;
  const float* row = x2 + nc * P2304;
  float s = 0.f;
#pragma unroll
  for (int i = 0; i < 9; i++) s += row[t + 256 * i];
  float w = wredSum(s);
  if ((t & 63) == 0) red[t >> 6] = w;
  __syncthreads();
  if (t == 0) xave[nc] = (red[0] + red[1] + red[2] + red[3]) * (1.0f / 2304.0f);
}

// l2-normalize x_ave over channels
__global__ void xan_kernel(const float* __restrict__ xave, float* __restrict__ xan){
  __shared__ float red[2];
  int n = blockIdx.x, t = threadIdx.x; // 128 threads
  float v = xave[n * 128 + t];
  float w = wredSum(v * v);
  if ((t & 63) == 0) red[t >> 6] = w;
  __syncthreads();
  float norm = fmaxf(sqrtf(red[0] + red[1]), 1e-12f);
  xan[n * 128 + t] = v / norm;
}

// cos[n,p] = <xan, x2hat[:,p]>
__global__ void cos_kernel(const float* __restrict__ x2, const float* __restrict__ xan,
                           float* __restrict__ cosb){
  int idx = blockIdx.x * 256 + threadIdx.x;
  if (idx >= N_IMG * P2304) return;
  int n = idx / P2304;
  int p = idx - n * P2304;
  const float* xp = x2 + n * C2 * P2304 + p;
  const float* an = xan + n * 128;
  float dot = 0.f, ss = 0.f;
  for (int c = 0; c < 128; c++){
    float v = xp[c * P2304];
    dot += an[c] * v;
    ss  += v * v;
  }
  cosb[idx] = dot / fmaxf(sqrtf(ss), 1e-12f);
}

// ---------------- LBP code + normalization + qlv ----------------
__global__ void lbp_kernel(const float* __restrict__ cosb, float* __restrict__ code,
                           float* __restrict__ qlv){
  __shared__ float red[4];
  int n = blockIdx.x;
  int l = threadIdx.x;           // 256 positions, l = ir*16+ic
  int ir = l >> 4, ic = l & 15;
  const float* cn = cosb + n * P2304;
  float cs4 = cn[(16 + ir) * 48 + (16 + ic)];
  const float wts[9] = {1.f, 2.f, 4.f, 8.f, 0.f, 16.f, 32.f, 64.f, 128.f};
  float codev = 0.f;
#pragma unroll
  for (int j = 0; j < 9; j++){
    int jr = j / 3, jc = j - 3 * (j / 3);
    float vv = cn[(jr * 16 + ir) * 48 + (jc * 16 + ic)];
    if (vv > cs4) codev += wts[j];
  }
  float w;
  w = wredMin(codev);
  if ((l & 63) == 0) red[l >> 6] = w;
  __syncthreads();
  float mn = fminf(fminf(red[0], red[1]), fminf(red[2], red[3]));
  __syncthreads();
  w = wredMax(codev);
  if ((l & 63) == 0) red[l >> 6] = w;
  __syncthreads();
  float mx = fmaxf(fmaxf(red[0], red[1]), fmaxf(red[2], red[3]));
  __syncthreads();
  float cd = (codev - mn) / (mx - mn);
  w = wredMin(cd);
  if ((l & 63) == 0) red[l >> 6] = w;
  __syncthreads();
  float cmin = fminf(fminf(red[0], red[1]), fminf(red[2], red[3]));
  __syncthreads();
  w = wredMax(cd);
  if ((l & 63) == 0) red[l >> 6] = w;
  __syncthreads();
  float cmax = fmaxf(fmaxf(red[0], red[1]), fmaxf(red[2], red[3]));
  code[n * 256 + l] = cd;
  if (l < 128){
    float tmp = (float)(2 * l + 1) * (1.0f / 256.0f);
    qlv[n * 128 + l] = tmp * (cmax - cmin) + cmin;
  }
}

// quantT[n][lev][p] = thresholded soft-assignment (transposed for coalescing)
__global__ void quant_kernel(const float* __restrict__ code, const float* __restrict__ qlv,
                             float* __restrict__ quantT){
  __shared__ float cs[256];
  __shared__ float qs[128];
  int n = blockIdx.x, t = threadIdx.x;
  cs[t] = code[n * 256 + t];
  if (t < 128) qs[t] = qlv[n * 128 + t];
  __syncthreads();
  float thr = 1.0f - (qs[1] - qs[0]);
  float* dst = quantT + n * LEV * 256;
#pragma unroll 4
  for (int i = 0; i < 128; i++){
    int v = t + 256 * i;
    int lv = v >> 8;
    int p = v & 255;
    float qq = 1.0f - fabsf(qs[lv] - cs[p]);
    dst[v] = (qq > thr) ? qq : 0.f;
  }
}

// sta[n][i] = sum_p quant / total
__global__ void sta_kernel(const float* __restrict__ quantT, float* __restrict__ sta){
  __shared__ float red[2];
  int n = blockIdx.x, i = threadIdx.x; // 128 threads
  const float* qr = quantT + (n * LEV + i) * 256;
  float s = 0.f;
  for (int p = 0; p < 256; p++) s += qr[p];
  float w = wredSum(s);
  if ((i & 63) == 0) red[i >> 6] = w;
  __syncthreads();
  float tot = red[0] + red[1];
  sta[n * 128 + i] = s / tot;
}

// h1 = leaky(f1_w @ [qlv; sta])
__global__ void h1_kernel(const float* __restrict__ f1w, const float* __restrict__ qlv,
                          const float* __restrict__ sta, float* __restrict__ h1){
  int idx = blockIdx.x * 256 + threadIdx.x;
  if (idx >= N_IMG * 64 * 128) return;
  int l = idx & 127;
  int n = idx >> 13;
  int o = (idx >> 7) & 63;
  float a = f1w[o * 2] * qlv[n * 128 + l] + f1w[o * 2 + 1] * sta[n * 128 + l];
  h1[idx] = a > 0.f ? a : 0.01f * a;
}

// generic per-image "W @ B" with optional bn+relu: C[n,o,l] = act(sum_c Wm[o,c]*B[n,c,l])
__global__ void gemm_w_kernel(const float* __restrict__ Wm, const float* __restrict__ B,
                              float* __restrict__ Cout, int Cdim, int O, int total, int mode,
                              const float* __restrict__ g, const float* __restrict__ bb,
                              const float* __restrict__ mm, const float* __restrict__ vv){
  int idx = blockIdx.x * 256 + threadIdx.x;
  if (idx >= total) return;
  int per_n = (O >> 2) << 7;
  int n = idx / per_n;
  int rem = idx - n * per_n;
  int o0 = (rem >> 7) << 2;
  int l = rem & 127;
  const float* Bn = B + (n * Cdim) * 128 + l;
  const float* w0 = Wm + (o0 + 0) * Cdim;
  const float* w1 = Wm + (o0 + 1) * Cdim;
  const float* w2 = Wm + (o0 + 2) * Cdim;
  const float* w3 = Wm + (o0 + 3) * Cdim;
  float a0 = 0, a1 = 0, a2 = 0, a3 = 0;
  for (int c = 0; c < Cdim; c++){
    float bv = Bn[c * 128];
    a0 += w0[c] * bv; a1 += w1[c] * bv; a2 += w2[c] * bv; a3 += w3[c] * bv;
  }
  float av[4] = {a0, a1, a2, a3};
#pragma unroll
  for (int j = 0; j < 4; j++){
    int o = o0 + j;
    float val = av[j];
    if (mode == 1){
      float s = g[o] * (1.0f / sqrtf(vv[o] + 1e-5f));
      val = (val - mm[o]) * s + bb[o];
      val = fmaxf(val, 0.f);
    }
    Cout[(n * O + o) * 128 + l] = val;
  }
}

// s = concat([h2, broadcast(x_ave)], channel dim)
__global__ void concat_kernel(const float* __restrict__ h2, const float* __restrict__ xave,
                              float* __restrict__ s){
  int idx = blockIdx.x * 256 + threadIdx.x;
  if (idx >= N_IMG * 256 * 128) return;
  int l = idx & 127;
  int c = (idx >> 7) & 255;
  int n = idx >> 15;
  s[idx] = (c < 128) ? h2[(n * 128 + c) * 128 + l] : xave[n * 128 + (c - 128)];
}

// sc[n,l,m] = sum_c k[n,c,l]*q[n,c,m]
__global__ void attn_sc_kernel(const float* __restrict__ k, const float* __restrict__ q,
                               float* __restrict__ sc){
  int idx = blockIdx.x * 256 + threadIdx.x;
  if (idx >= N_IMG * 32 * 128) return;
  int m = idx & 127;
  int l0 = ((idx >> 7) & 31) << 2;
  int n = idx >> 12;
  const float* kn = k + n * 256 * 128;
  const float* qn = q + n * 256 * 128 + m;
  float a0 = 0, a1 = 0, a2 = 0, a3 = 0;
  for (int c = 0; c < 256; c++){
    float qv = qn[c * 128];
    const float* kr = kn + c * 128 + l0;
    a0 += kr[0] * qv; a1 += kr[1] * qv; a2 += kr[2] * qv; a3 += kr[3] * qv;
  }
  float* dst = sc + (n * 128 + l0) * 128 + m;
  dst[0] = a0; dst[128] = a1; dst[256] = a2; dst[384] = a3;
}

__global__ void softmax_kernel(float* __restrict__ sc){
  __shared__ float red[2];
  int row = blockIdx.x;
  int t = threadIdx.x; // 128
  float v = sc[row * 128 + t];
  float w = wredMax(v);
  if ((t & 63) == 0) red[t >> 6] = w;
  __syncthreads();
  float mx = fmaxf(red[0], red[1]);
  float e = expf(v - mx);
  float s = wredSum(e);
  __syncthreads();
  if ((t & 63) == 0) red[t >> 6] = s;
  __syncthreads();
  sc[row * 128 + t] = e / (red[0] + red[1]);
}

__global__ void transpose_sc_kernel(const float* __restrict__ sc, float* __restrict__ scT){
  int idx = blockIdx.x * 256 + threadIdx.x;
  if (idx >= N_IMG * 128 * 128) return;
  int l = idx & 127;
  int m = (idx >> 7) & 127;
  int n = idx >> 14;
  scT[idx] = sc[(n * 128 + l) * 128 + m];
}

// f[n,c,l] = sum_m v[n,c,m]*scT[n,m,l]
__global__ void attn_f_kernel(const float* __restrict__ vb, const float* __restrict__ scT,
                              float* __restrict__ f){
  int idx = blockIdx.x * 256 + threadIdx.x;
  if (idx >= N_IMG * 64 * 128) return;
  int l = idx & 127;
  int c0 = ((idx >> 7) & 63) << 2;
  int n = idx >> 13;
  const float* vn = vb + (n * 256 + c0) * 128;
  const float* sn = scT + n * 128 * 128 + l;
  float a0 = 0, a1 = 0, a2 = 0, a3 = 0;
  for (int m = 0; m < 128; m++){
    float sv = sn[m * 128];
    a0 += vn[m] * sv; a1 += vn[128 + m] * sv; a2 += vn[256 + m] * sv; a3 += vn[384 + m] * sv;
  }
  float* dst = f + (n * 256 + c0) * 128 + l;
  dst[0] = a0; dst[128] = a1; dst[256] = a2; dst[384] = a3;
}

// outs[n,c,p] = sum_lev g[n,c,lev]*quantT[n,lev,p]
__global__ void final_kernel(const float* __restrict__ g, const float* __restrict__ quantT,
                             float* __restrict__ outs){
  int idx = blockIdx.x * 256 + threadIdx.x;
  if (idx >= N_IMG * 64 * 256) return;
  int p = idx & 255;
  int c0 = ((idx >> 8) & 63) << 2;
  int n = idx >> 14;
  const float* gn = g + (n * 256 + c0) * 128;
  const float* qn = quantT + (n * LEV) * 256 + p;
  float a0 = 0, a1 = 0, a2 = 0, a3 = 0;
  for (int lv = 0; lv < 128; lv++){
    float qv = qn[lv * 256];
    a0 += gn[lv] * qv; a1 += gn[128 + lv] * qv; a2 += gn[256 + lv] * qv; a3 += gn[384 + lv] * qv;
  }
  float* dst = outs + (n * 256 + c0) * 256 + p;
  dst[0] = a0; dst[256] = a1; dst[512] = a2; dst[768] = a3;
}

// bilinear 16x16 -> 48x48 (align_corners-style linspace(0,15,48))
__global__ void resize_kernel(const float* __restrict__ outs, float* __restrict__ dout){
  int idx = blockIdx.x * 256 + threadIdx.x;
  if (idx >= N_IMG * 256 * P2304) return;
  int ow = idx % 48;
  int tmp = idx / 48;
  int oh = tmp % 48;
  int nc = tmp / 48;
  const float* src = outs + nc * 256;
  float fy = oh * (15.0f / 47.0f);
  float fx = ow * (15.0f / 47.0f);
  int y0 = (int)fy;
  int x0 = (int)fx;
  int y1 = min(y0 + 1, 15);
  int x1 = min(x0 + 1, 15);
  float wy = fy - (float)y0;
  float wx = fx - (float)x0;
  float v00 = src[y0 * 16 + x0], v01 = src[y0 * 16 + x1];
  float v10 = src[y1 * 16 + x0], v11 = src[y1 * 16 + x1];
  dout[idx] = v00 * (1.f - wy) * (1.f - wx) + v01 * (1.f - wy) * wx
            + v10 * wy * (1.f - wx) + v11 * wy * wx;
}

// ---------------- launcher ----------------
extern "C" void kernel_launch(void* const* d_in, const int* in_sizes, int n_in,
                              void* d_out, int out_size, void* d_ws, size_t ws_size,
                              hipStream_t stream)
{
  const float* x       = (const float*)d_in[0];
  const float* conv1_w = (const float*)d_in[1];
  const float* bn1_g   = (const float*)d_in[2];
  const float* bn1_b   = (const float*)d_in[3];
  const float* bn1_m   = (const float*)d_in[4];
  const float* bn1_v   = (const float*)d_in[5];
  const float* conv2_w = (const float*)d_in[6];
  const float* f1_w    = (const float*)d_in[7];
  const float* f2_w    = (const float*)d_in[8];
  const float* f2_g    = (const float*)d_in[9];
  const float* f2_b    = (const float*)d_in[10];
  const float* f2_m    = (const float*)d_in[11];
  const float* f2_v    = (const float*)d_in[12];
  const float* out1_w  = (const float*)d_in[13];
  const float* out1_g  = (const float*)d_in[14];
  const float* out1_b  = (const float*)d_in[15];
  const float* out1_m  = (const float*)d_in[16];
  const float* out1_v  = (const float*)d_in[17];
  const float* k_w     = (const float*)d_in[18];
  const float* q_w     = (const float*)d_in[19];
  const float* v_w     = (const float*)d_in[20];
  const float* out_w   = (const float*)d_in[21];
  const float* out_g   = (const float*)d_in[22];
  const float* out_b   = (const float*)d_in[23];
  const float* out_m   = (const float*)d_in[24];
  const float* out_v   = (const float*)d_in[25];

  float* ws = (float*)d_ws;
  float* dout = (float*)d_out;

  // large buffers
  float* w_y   = ws;                  // 18874368 f (y: 32x256x2304) -- dead after conv2
  float* w_x2  = ws + 18874368;       // 9437184 f
  float* w_wg  = ws + 28311552;       // 1179648 f (reordered conv1 weights)
  float* w_w2t = ws + 29491200;       // 32768 f  => total 29523968 floats = 118.1 MB
  // small buffers reuse the y region (only written after conv2 consumed y)
  float* w_xave = w_y + 0;            // 4096
  float* w_xan  = w_y + 4096;         // 4096
  float* w_cos  = w_y + 8192;         // 73728
  float* w_code = w_y + 81920;        // 8192
  float* w_qlv  = w_y + 90112;        // 4096
  float* w_sta  = w_y + 94208;        // 4096
  float* w_quant= w_y + 98304;        // 1048576 (quantT [n][lev][p])
  float* w_h1   = w_y + 1146880;      // 262144
  float* w_h2   = w_y + 1409024;      // 524288
  float* w_s    = w_y + 1933312;      // 1048576
  float* w_k    = w_y + 2981888;      // 1048576
  float* w_q    = w_y + 4030464;      // 1048576
  float* w_v    = w_y + 5079040;      // 1048576
  float* w_sc   = w_y + 6127616;      // 524288
  float* w_scT  = w_y + 6651904;      // 524288
  float* w_f    = w_y + 7176192;      // 1048576
  float* w_g    = w_y + 8224768;      // 1048576
  float* w_outs = w_y + 9273344;      // 2097152
  float* w_s2   = w_y + 11370496;     // 1048576 (ends 12419072 < 18874368)

  reorder_w1_kernel<<<4608, 256, 0, stream>>>(conv1_w, w_wg);
  transpose_w2_kernel<<<128, 256, 0, stream>>>(conv2_w, w_w2t);
  conv1_kernel<<<1152, 256, 0, stream>>>(x, w_wg, bn1_g, bn1_b, bn1_m, bn1_v, w_y);
  conv2_kernel<<<576, 256, 0, stream>>>(w_y, w_w2t, w_x2);
  xave_kernel<<<4096, 256, 0, stream>>>(w_x2, w_xave);
  xan_kernel<<<32, 128, 0, stream>>>(w_xave, w_xan);
  cos_kernel<<<288, 256, 0, stream>>>(w_x2, w_xan, w_cos);
  lbp_kernel<<<32, 256, 0, stream>>>(w_cos, w_code, w_qlv);
  quant_kernel<<<32, 256, 0, stream>>>(w_code, w_qlv, w_quant);
  sta_kernel<<<32, 128, 0, stream>>>(w_quant, w_sta);
  h1_kernel<<<1024, 256, 0, stream>>>(f1_w, w_qlv, w_sta, w_h1);
  gemm_w_kernel<<<512, 256, 0, stream>>>(f2_w, w_h1, w_h2, 64, 128, N_IMG * 32 * 128, 1,
                                         f2_g, f2_b, f2_m, f2_v);
  concat_kernel<<<4096, 256, 0, stream>>>(w_h2, w_xave, w_s);
  gemm_w_kernel<<<1024, 256, 0, stream>>>(out1_w, w_s, w_s2, 256, 256, N_IMG * 64 * 128, 1,
                                          out1_g, out1_b, out1_m, out1_v);
  gemm_w_kernel<<<1024, 256, 0, stream>>>(k_w, w_s2, w_k, 256, 256, N_IMG * 64 * 128, 0,
                                          nullptr, nullptr, nullptr, nullptr);
  gemm_w_kernel<<<1024, 256, 0, stream>>>(q_w, w_s2, w_q, 256, 256, N_IMG * 64 * 128, 0,
                                          nullptr, nullptr, nullptr, nullptr);
  gemm_w_kernel<<<1024, 256, 0, stream>>>(v_w, w_s2, w_v, 256, 256, N_IMG * 64 * 128, 0,
                                          nullptr, nullptr, nullptr, nullptr);
  attn_sc_kernel<<<512, 256, 0, stream>>>(w_k, w_q, w_sc);
  softmax_kernel<<<4096, 128, 0, stream>>>(w_sc);
  transpose_sc_kernel<<<2048, 256, 0, stream>>>(w_sc, w_scT);
  attn_f_kernel<<<1024, 256, 0, stream>>>(w_v, w_scT, w_f);
  gemm_w_kernel<<<1024, 256, 0, stream>>>(out_w, w_f, w_g, 256, 256, N_IMG * 64 * 128, 1,
                                          out_g, out_b, out_m, out_v);
  final_kernel<<<2048, 256, 0, stream>>>(w_g, w_quant, w_outs);
  resize_kernel<<<73728, 256, 0, stream>>>(w_outs, dout);
}

// Round 2
// 1877.890 us; speedup vs baseline: 2.0034x; 2.0034x over previous
//
#include <hip/hip_runtime.h>
#include <math.h>

#define N_IMG 32
#define P2304 2304
#define CIN 512
#define CMID 256
#define C2 128
#define LEV 128

typedef _Float16 half8 __attribute__((ext_vector_type(8)));
typedef float f32x16 __attribute__((ext_vector_type(16)));

// ---------------- wave/block reduction helpers (wave = 64) ----------------
__device__ __forceinline__ float wredSum(float v){
#pragma unroll
  for (int o = 32; o > 0; o >>= 1) v += __shfl_down(v, o, 64);
  return v;
}
__device__ __forceinline__ float wredMax(float v){
#pragma unroll
  for (int o = 32; o > 0; o >>= 1) v = fmaxf(v, __shfl_down(v, o, 64));
  return v;
}
__device__ __forceinline__ float wredMin(float v){
#pragma unroll
  for (int o = 32; o > 0; o >>= 1) v = fminf(v, __shfl_down(v, o, 64));
  return v;
}

// ---------------- weight prepack: split f32 -> (hi, lo*2^11) f16 frags ----
// Fragment order: frag index fi = ((kt*COTN + cot)*4 + c32)*64 + lam,
// holding 8 f16: element j is W[co = cot*128 + c32*32 + (lam&31)]
//                             [k  = kt*16 + (lam>>5)*8 + j]
__global__ void prep_w1_kernel(const float* __restrict__ w1,
                               uint4* __restrict__ Wh, uint4* __restrict__ Wl){
  int fid = blockIdx.x * 256 + threadIdx.x;     // 147456 frags
  int lam = fid & 63;
  int c32 = (fid >> 6) & 3;
  int cot = (fid >> 8) & 1;
  int kt  = fid >> 9;                           // 0..287
  int co = cot * 128 + c32 * 32 + (lam & 31);
  half8 vh, vl;
#pragma unroll
  for (int j = 0; j < 8; ++j){
    int k = kt * 16 + ((lam >> 5) << 3) + j;    // 0..4607
    int r = k >> 9;                             // tap
    int ci = k & 511;
    float v = w1[co * (CIN * 9) + ci * 9 + r];
    _Float16 h = (_Float16)v;
    vh[j] = h;
    vl[j] = (_Float16)((v - (float)h) * 2048.0f);
  }
  Wh[fid] = *(uint4*)&vh;
  Wl[fid] = *(uint4*)&vl;
}

__global__ void prep_w2_kernel(const float* __restrict__ w2,
                               uint4* __restrict__ Wh, uint4* __restrict__ Wl){
  int fid = blockIdx.x * 256 + threadIdx.x;     // 4096 frags
  int lam = fid & 63;
  int c32 = (fid >> 6) & 3;
  int kt  = fid >> 8;                           // 0..15
  int co = c32 * 32 + (lam & 31);
  half8 vh, vl;
#pragma unroll
  for (int j = 0; j < 8; ++j){
    int k = kt * 16 + ((lam >> 5) << 3) + j;    // 0..255
    float v = w2[co * CMID + k];
    _Float16 h = (_Float16)v;
    vh[j] = h;
    vl[j] = (_Float16)((v - (float)h) * 2048.0f);
  }
  Wh[fid] = *(uint4*)&vh;
  Wl[fid] = *(uint4*)&vl;
}

// s1 = g/sqrt(v+eps), t1 = b - m*s1  (bn folded to y*s1 + t1)
__global__ void prep_bn_kernel(const float* __restrict__ g1, const float* __restrict__ b1,
                               const float* __restrict__ m1, const float* __restrict__ v1,
                               float* __restrict__ s1, float* __restrict__ t1){
  int c = threadIdx.x;  // 256
  float s = g1[c] * (1.0f / sqrtf(v1[c] + 1e-5f));
  s1[c] = s;
  t1[c] = b1[c] - m1[c] * s;
}

// ---------------- split-f16 MFMA conv (3x3 SAME or 1x1) -------------------
// GEMM: M = COTN*128 (co), N = 2304 (p), K = R*CPT. Block tile 128co x 128p,
// 4 waves, each wave 64x64 via 2x2 mfma_32x32x16 tiles, dual accumulators
// (hh and scaled cross terms). LDS frags wave-linear -> conflict-free.
template<int R, int CPT, int COTN, bool BN>
__global__ __launch_bounds__(256, 2) void conv_mfma_kernel(
    const float* __restrict__ in, const uint4* __restrict__ Wh, const uint4* __restrict__ Wl,
    const float* __restrict__ s1, const float* __restrict__ t1, float* __restrict__ out)
{
  __shared__ _Float16 Ah[2048], Al[2048], Bh[2048], Bl[2048];
  const int t = threadIdx.x;
  const int lam = t & 63;
  const int g = t >> 6;          // wave id; also c32 group (A stage) / p32 group (B stage)

  int n, pt_blk, cot;
  if (COTN == 2){
    // XCD-aware swizzle: blockIdx%8 -> XCD; give each XCD a private n-range.
    int xcd = blockIdx.x & 7;
    int rest = blockIdx.x >> 3;  // 0..143
    n = xcd * 4 + rest / 36;
    int inner = rest % 36;
    pt_blk = inner % 18;
    cot = inner / 18;
  } else {
    pt_blk = blockIdx.x % 18;
    cot = 0;
    n = blockIdx.x / 18;
  }
  const int pbase = pt_blk * 128;
  const int cobase = cot * 128;

  // B staging coords (fixed per thread)
  const int khi = lam >> 5;                    // 0/1: k-half of fragment
  const int pp = (g << 5) + (lam & 31);        // 0..127 within p-tile
  const int p = pbase + pp;
  const int ph = p / 48, pw = p - ph * 48;
  const float* in_n = in + (size_t)n * CPT * P2304;

  f32x16 acc_hh[2][2], acc_x[2][2];
#pragma unroll
  for (int a = 0; a < 2; ++a)
#pragma unroll
    for (int b = 0; b < 2; ++b){
#pragma unroll
      for (int e = 0; e < 16; ++e){ acc_hh[a][b][e] = 0.f; acc_x[a][b][e] = 0.f; }
    }

  const int KTPR = CPT / 16;
  for (int r = 0; r < R; ++r){
    const int dh = (R == 1) ? 0 : (r / 3 - 1);
    const int dw = (R == 1) ? 0 : (r - (r / 3) * 3 - 1);
    const int hh_ = ph + dh, ww_ = pw + dw;
    const bool valid = ((unsigned)hh_ < 48u) & ((unsigned)ww_ < 48u);
    const float* src0 = in_n + (valid ? (hh_ * 48 + ww_) : 0) + (size_t)(khi * 8) * P2304;
    for (int it = 0; it < KTPR; ++it){
      const int kt = r * KTPR + it;
      __syncthreads();
      // stage A (weights, pre-packed fragments): thread t -> frag (c32=g, lam)
      {
        int fi = ((kt * COTN + cot) * 4 + g) * 64 + lam;
        *(uint4*)&Ah[t * 8] = Wh[fi];
        *(uint4*)&Al[t * 8] = Wl[fi];
      }
      // stage B (input, f32 -> hi/lo f16): thread t -> frag (p32=g, lam)
      {
        const float* src = src0 + it * 16 * P2304;
        half8 vh, vl;
#pragma unroll
        for (int j = 0; j < 8; ++j){
          float v = valid ? src[j * P2304] : 0.0f;
          _Float16 h = (_Float16)v;
          vh[j] = h;
          vl[j] = (_Float16)((v - (float)h) * 2048.0f);
        }
        *(half8*)&Bh[t * 8] = vh;
        *(half8*)&Bl[t * 8] = vl;
      }
      __syncthreads();
      // fragments for this wave's 64x64 quadrant
      const int ct0 = (g & 1) * 2, pt0 = (g >> 1) * 2;
      half8 fAh[2], fAl[2], fBh[2], fBl[2];
#pragma unroll
      for (int a = 0; a < 2; ++a){
        fAh[a] = *(half8*)&Ah[((ct0 + a) * 64 + lam) * 8];
        fAl[a] = *(half8*)&Al[((ct0 + a) * 64 + lam) * 8];
        fBh[a] = *(half8*)&Bh[((pt0 + a) * 64 + lam) * 8];
        fBl[a] = *(half8*)&Bl[((pt0 + a) * 64 + lam) * 8];
      }
#pragma unroll
      for (int a = 0; a < 2; ++a)
#pragma unroll
        for (int b = 0; b < 2; ++b){
          acc_hh[a][b] = __builtin_amdgcn_mfma_f32_32x32x16_f16(fAh[a], fBh[b], acc_hh[a][b], 0, 0, 0);
          acc_x[a][b]  = __builtin_amdgcn_mfma_f32_32x32x16_f16(fAh[a], fBl[b], acc_x[a][b], 0, 0, 0);
          acc_x[a][b]  = __builtin_amdgcn_mfma_f32_32x32x16_f16(fAl[a], fBh[b], acc_x[a][b], 0, 0, 0);
        }
    }
  }

  // epilogue: combine hi/lo passes, optional bn+leaky, store f32
  const int M = COTN * 128;
#pragma unroll
  for (int a = 0; a < 2; ++a){
    const int ctile = (g & 1) * 2 + a;
#pragma unroll
    for (int b = 0; b < 2; ++b){
      const int ptile = (g >> 1) * 2 + b;
      const int pg = pbase + ptile * 32 + (lam & 31);
#pragma unroll
      for (int rg = 0; rg < 16; ++rg){
        const int row = (rg & 3) + 8 * (rg >> 2) + 4 * (lam >> 5);
        const int co = cobase + ctile * 32 + row;
        float val = acc_hh[a][b][rg] + acc_x[a][b][rg] * (1.0f / 2048.0f);
        if (BN){
          val = val * s1[co] + t1[co];
          val = val > 0.f ? val : 0.01f * val;
        }
        out[((size_t)n * M + co) * P2304 + pg] = val;
      }
    }
  }
}

// ---------------- x_ave (mean over 2304 positions per (n,c)) ----------------
__global__ void xave_kernel(const float* __restrict__ x2, float* __restrict__ xave){
  __shared__ float red[4];
  int nc = blockIdx.x, t = threadIdx.x;
  const float* row = x2 + nc * P2304;
  float s = 0.f;
#pragma unroll
  for (int i = 0; i < 9; i++) s += row[t + 256 * i];
  float w = wredSum(s);
  if ((t & 63) == 0) red[t >> 6] = w;
  __syncthreads();
  if (t == 0) xave[nc] = (red[0] + red[1] + red[2] + red[3]) * (1.0f / 2304.0f);
}

// l2-normalize x_ave over channels
__global__ void xan_kernel(const float* __restrict__ xave, float* __restrict__ xan){
  __shared__ float red[2];
  int n = blockIdx.x, t = threadIdx.x; // 128 threads
  float v = xave[n * 128 + t];
  float w = wredSum(v * v);
  if ((t & 63) == 0) red[t >> 6] = w;
  __syncthreads();
  float norm = fmaxf(sqrtf(red[0] + red[1]), 1e-12f);
  xan[n * 128 + t] = v / norm;
}

// cos[n,p] = <xan, x2hat[:,p]>
__global__ void cos_kernel(const float* __restrict__ x2, const float* __restrict__ xan,
                           float* __restrict__ cosb){
  int idx = blockIdx.x * 256 + threadIdx.x;
  if (idx >= N_IMG * P2304) return;
  int n = idx / P2304;
  int p = idx - n * P2304;
  const float* xp = x2 + n * C2 * P2304 + p;
  const float* an = xan + n * 128;
  float dot = 0.f, ss = 0.f;
  for (int c = 0; c < 128; c++){
    float v = xp[c * P2304];
    dot += an[c] * v;
    ss  += v * v;
  }
  cosb[idx] = dot / fmaxf(sqrtf(ss), 1e-12f);
}

// ---------------- LBP code + normalization + qlv ----------------
__global__ void lbp_kernel(const float* __restrict__ cosb, float* __restrict__ code,
                           float* __restrict__ qlv){
  __shared__ float red[4];
  int n = blockIdx.x;
  int l = threadIdx.x;           // 256 positions, l = ir*16+ic
  int ir = l >> 4, ic = l & 15;
  const float* cn = cosb + n * P2304;
  float cs4 = cn[(16 + ir) * 48 + (16 + ic)];
  const float wts[9] = {1.f, 2.f, 4.f, 8.f, 0.f, 16.f, 32.f, 64.f, 128.f};
  float codev = 0.f;
#pragma unroll
  for (int j = 0; j < 9; j++){
    int jr = j / 3, jc = j - 3 * (j / 3);
    float vv = cn[(jr * 16 + ir) * 48 + (jc * 16 + ic)];
    if (vv > cs4) codev += wts[j];
  }
  float w;
  w = wredMin(codev);
  if ((l & 63) == 0) red[l >> 6] = w;
  __syncthreads();
  float mn = fminf(fminf(red[0], red[1]), fminf(red[2], red[3]));
  __syncthreads();
  w = wredMax(codev);
  if ((l & 63) == 0) red[l >> 6] = w;
  __syncthreads();
  float mx = fmaxf(fmaxf(red[0], red[1]), fmaxf(red[2], red[3]));
  __syncthreads();
  float cd = (codev - mn) / (mx - mn);
  w = wredMin(cd);
  if ((l & 63) == 0) red[l >> 6] = w;
  __syncthreads();
  float cmin = fminf(fminf(red[0], red[1]), fminf(red[2], red[3]));
  __syncthreads();
  w = wredMax(cd);
  if ((l & 63) == 0) red[l >> 6] = w;
  __syncthreads();
  float cmax = fmaxf(fmaxf(red[0], red[1]), fmaxf(red[2], red[3]));
  code[n * 256 + l] = cd;
  if (l < 128){
    float tmp = (float)(2 * l + 1) * (1.0f / 256.0f);
    qlv[n * 128 + l] = tmp * (cmax - cmin) + cmin;
  }
}

// quantT[n][lev][p] = thresholded soft-assignment (transposed for coalescing)
__global__ void quant_kernel(const float* __restrict__ code, const float* __restrict__ qlv,
                             float* __restrict__ quantT){
  __shared__ float cs[256];
  __shared__ float qs[128];
  int n = blockIdx.x, t = threadIdx.x;
  cs[t] = code[n * 256 + t];
  if (t < 128) qs[t] = qlv[n * 128 + t];
  __syncthreads();
  float thr = 1.0f - (qs[1] - qs[0]);
  float* dst = quantT + n * LEV * 256;
#pragma unroll 4
  for (int i = 0; i < 128; i++){
    int v = t + 256 * i;
    int lv = v >> 8;
    int p = v & 255;
    float qq = 1.0f - fabsf(qs[lv] - cs[p]);
    dst[v] = (qq > thr) ? qq : 0.f;
  }
}

// sta[n][i] = sum_p quant / total
__global__ void sta_kernel(const float* __restrict__ quantT, float* __restrict__ sta){
  __shared__ float red[2];
  int n = blockIdx.x, i = threadIdx.x; // 128 threads
  const float* qr = quantT + (n * LEV + i) * 256;
  float s = 0.f;
  for (int p = 0; p < 256; p++) s += qr[p];
  float w = wredSum(s);
  if ((i & 63) == 0) red[i >> 6] = w;
  __syncthreads();
  float tot = red[0] + red[1];
  sta[n * 128 + i] = s / tot;
}

// h1 = leaky(f1_w @ [qlv; sta])
__global__ void h1_kernel(const float* __restrict__ f1w, const float* __restrict__ qlv,
                          const float* __restrict__ sta, float* __restrict__ h1){
  int idx = blockIdx.x * 256 + threadIdx.x;
  if (idx >= N_IMG * 64 * 128) return;
  int l = idx & 127;
  int n = idx >> 13;
  int o = (idx >> 7) & 63;
  float a = f1w[o * 2] * qlv[n * 128 + l] + f1w[o * 2 + 1] * sta[n * 128 + l];
  h1[idx] = a > 0.f ? a : 0.01f * a;
}

// generic per-image "W @ B" with optional bn+relu: C[n,o,l] = act(sum_c Wm[o,c]*B[n,c,l])
__global__ void gemm_w_kernel(const float* __restrict__ Wm, const float* __restrict__ B,
                              float* __restrict__ Cout, int Cdim, int O, int total, int mode,
                              const float* __restrict__ g, const float* __restrict__ bb,
                              const float* __restrict__ mm, const float* __restrict__ vv){
  int idx = blockIdx.x * 256 + threadIdx.x;
  if (idx >= total) return;
  int per_n = (O >> 2) << 7;
  int n = idx / per_n;
  int rem = idx - n * per_n;
  int o0 = (rem >> 7) << 2;
  int l = rem & 127;
  const float* Bn = B + (n * Cdim) * 128 + l;
  const float* w0 = Wm + (o0 + 0) * Cdim;
  const float* w1 = Wm + (o0 + 1) * Cdim;
  const float* w2 = Wm + (o0 + 2) * Cdim;
  const float* w3 = Wm + (o0 + 3) * Cdim;
  float a0 = 0, a1 = 0, a2 = 0, a3 = 0;
  for (int c = 0; c < Cdim; c++){
    float bv = Bn[c * 128];
    a0 += w0[c] * bv; a1 += w1[c] * bv; a2 += w2[c] * bv; a3 += w3[c] * bv;
  }
  float av[4] = {a0, a1, a2, a3};
#pragma unroll
  for (int j = 0; j < 4; j++){
    int o = o0 + j;
    float val = av[j];
    if (mode == 1){
      float s = g[o] * (1.0f / sqrtf(vv[o] + 1e-5f));
      val = (val - mm[o]) * s + bb[o];
      val = fmaxf(val, 0.f);
    }
    Cout[(n * O + o) * 128 + l] = val;
  }
}

// s = concat([h2, broadcast(x_ave)], channel dim)
__global__ void concat_kernel(const float* __restrict__ h2, const float* __restrict__ xave,
                              float* __restrict__ s){
  int idx = blockIdx.x * 256 + threadIdx.x;
  if (idx >= N_IMG * 256 * 128) return;
  int l = idx & 127;
  int c = (idx >> 7) & 255;
  int n = idx >> 15;
  s[idx] = (c < 128) ? h2[(n * 128 + c) * 128 + l] : xave[n * 128 + (c - 128)];
}

// sc[n,l,m] = sum_c k[n,c,l]*q[n,c,m]
__global__ void attn_sc_kernel(const float* __restrict__ k, const float* __restrict__ q,
                               float* __restrict__ sc){
  int idx = blockIdx.x * 256 + threadIdx.x;
  if (idx >= N_IMG * 32 * 128) return;
  int m = idx & 127;
  int l0 = ((idx >> 7) & 31) << 2;
  int n = idx >> 12;
  const float* kn = k + n * 256 * 128;
  const float* qn = q + n * 256 * 128 + m;
  float a0 = 0, a1 = 0, a2 = 0, a3 = 0;
  for (int c = 0; c < 256; c++){
    float qv = qn[c * 128];
    const float* kr = kn + c * 128 + l0;
    a0 += kr[0] * qv; a1 += kr[1] * qv; a2 += kr[2] * qv; a3 += kr[3] * qv;
  }
  float* dst = sc + (n * 128 + l0) * 128 + m;
  dst[0] = a0; dst[128] = a1; dst[256] = a2; dst[384] = a3;
}

__global__ void softmax_kernel(float* __restrict__ sc){
  __shared__ float red[2];
  int row = blockIdx.x;
  int t = threadIdx.x; // 128
  float v = sc[row * 128 + t];
  float w = wredMax(v);
  if ((t & 63) == 0) red[t >> 6] = w;
  __syncthreads();
  float mx = fmaxf(red[0], red[1]);
  float e = expf(v - mx);
  float s = wredSum(e);
  __syncthreads();
  if ((t & 63) == 0) red[t >> 6] = s;
  __syncthreads();
  sc[row * 128 + t] = e / (red[0] + red[1]);
}

__global__ void transpose_sc_kernel(const float* __restrict__ sc, float* __restrict__ scT){
  int idx = blockIdx.x * 256 + threadIdx.x;
  if (idx >= N_IMG * 128 * 128) return;
  int l = idx & 127;
  int m = (idx >> 7) & 127;
  int n = idx >> 14;
  scT[idx] = sc[(n * 128 + l) * 128 + m];
}

// f[n,c,l] = sum_m v[n,c,m]*scT[n,m,l]
__global__ void attn_f_kernel(const float* __restrict__ vb, const float* __restrict__ scT,
                              float* __restrict__ f){
  int idx = blockIdx.x * 256 + threadIdx.x;
  if (idx >= N_IMG * 64 * 128) return;
  int l = idx & 127;
  int c0 = ((idx >> 7) & 63) << 2;
  int n = idx >> 13;
  const float* vn = vb + (n * 256 + c0) * 128;
  const float* sn = scT + n * 128 * 128 + l;
  float a0 = 0, a1 = 0, a2 = 0, a3 = 0;
  for (int m = 0; m < 128; m++){
    float sv = sn[m * 128];
    a0 += vn[m] * sv; a1 += vn[128 + m] * sv; a2 += vn[256 + m] * sv; a3 += vn[384 + m] * sv;
  }
  float* dst = f + (n * 256 + c0) * 128 + l;
  dst[0] = a0; dst[128] = a1; dst[256] = a2; dst[384] = a3;
}

// outs[n,c,p] = sum_lev g[n,c,lev]*quantT[n,lev,p]
__global__ void final_kernel(const float* __restrict__ g, const float* __restrict__ quantT,
                             float* __restrict__ outs){
  int idx = blockIdx.x * 256 + threadIdx.x;
  if (idx >= N_IMG * 64 * 256) return;
  int p = idx & 255;
  int c0 = ((idx >> 8) & 63) << 2;
  int n = idx >> 14;
  const float* gn = g + (n * 256 + c0) * 128;
  const float* qn = quantT + (n * LEV) * 256 + p;
  float a0 = 0, a1 = 0, a2 = 0, a3 = 0;
  for (int lv = 0; lv < 128; lv++){
    float qv = qn[lv * 256];
    a0 += gn[lv] * qv; a1 += gn[128 + lv] * qv; a2 += gn[256 + lv] * qv; a3 += gn[384 + lv] * qv;
  }
  float* dst = outs + (n * 256 + c0) * 256 + p;
  dst[0] = a0; dst[256] = a1; dst[512] = a2; dst[768] = a3;
}

// bilinear 16x16 -> 48x48 (align_corners-style linspace(0,15,48))
__global__ void resize_kernel(const float* __restrict__ outs, float* __restrict__ dout){
  int idx = blockIdx.x * 256 + threadIdx.x;
  if (idx >= N_IMG * 256 * P2304) return;
  int ow = idx % 48;
  int tmp = idx / 48;
  int oh = tmp % 48;
  int nc = tmp / 48;
  const float* src = outs + nc * 256;
  float fy = oh * (15.0f / 47.0f);
  float fx = ow * (15.0f / 47.0f);
  int y0 = (int)fy;
  int x0 = (int)fx;
  int y1 = min(y0 + 1, 15);
  int x1 = min(x0 + 1, 15);
  float wy = fy - (float)y0;
  float wx = fx - (float)x0;
  float v00 = src[y0 * 16 + x0], v01 = src[y0 * 16 + x1];
  float v10 = src[y1 * 16 + x0], v11 = src[y1 * 16 + x1];
  dout[idx] = v00 * (1.f - wy) * (1.f - wx) + v01 * (1.f - wy) * wx
            + v10 * wy * (1.f - wx) + v11 * wy * wx;
}

// ---------------- launcher ----------------
extern "C" void kernel_launch(void* const* d_in, const int* in_sizes, int n_in,
                              void* d_out, int out_size, void* d_ws, size_t ws_size,
                              hipStream_t stream)
{
  const float* x       = (const float*)d_in[0];
  const float* conv1_w = (const float*)d_in[1];
  const float* bn1_g   = (const float*)d_in[2];
  const float* bn1_b   = (const float*)d_in[3];
  const float* bn1_m   = (const float*)d_in[4];
  const float* bn1_v   = (const float*)d_in[5];
  const float* conv2_w = (const float*)d_in[6];
  const float* f1_w    = (const float*)d_in[7];
  const float* f2_w    = (const float*)d_in[8];
  const float* f2_g    = (const float*)d_in[9];
  const float* f2_b    = (const float*)d_in[10];
  const float* f2_m    = (const float*)d_in[11];
  const float* f2_v    = (const float*)d_in[12];
  const float* out1_w  = (const float*)d_in[13];
  const float* out1_g  = (const float*)d_in[14];
  const float* out1_b  = (const float*)d_in[15];
  const float* out1_m  = (const float*)d_in[16];
  const float* out1_v  = (const float*)d_in[17];
  const float* k_w     = (const float*)d_in[18];
  const float* q_w     = (const float*)d_in[19];
  const float* v_w     = (const float*)d_in[20];
  const float* out_w   = (const float*)d_in[21];
  const float* out_g   = (const float*)d_in[22];
  const float* out_b   = (const float*)d_in[23];
  const float* out_m   = (const float*)d_in[24];
  const float* out_v   = (const float*)d_in[25];

  float* ws = (float*)d_ws;
  float* dout = (float*)d_out;

  // large buffers
  float* w_y   = ws;                  // 18874368 f (y: 32x256x2304) -- dead after conv2
  float* w_x2  = ws + 18874368;       // 9437184 f
  float* w_W1h = ws + 28311552;       // 589824 f-slots = 1179648 f16 (packed frags)
  float* w_W1l = ws + 28901376;       // 589824
  float* w_W2h = ws + 29491200;       // 16384 f-slots = 32768 f16
  float* w_W2l = ws + 29507584;       // 16384
  float* w_s1  = ws + 29523968;       // 256
  float* w_t1  = ws + 29524224;       // 256  => total 29524480 f = 118.1 MB
  // small buffers reuse the y region (only written after conv2 consumed y)
  float* w_xave = w_y + 0;            // 4096
  float* w_xan  = w_y + 4096;         // 4096
  float* w_cos  = w_y + 8192;         // 73728
  float* w_code = w_y + 81920;        // 8192
  float* w_qlv  = w_y + 90112;        // 4096
  float* w_sta  = w_y + 94208;        // 4096
  float* w_quant= w_y + 98304;        // 1048576 (quantT [n][lev][p])
  float* w_h1   = w_y + 1146880;      // 262144
  float* w_h2   = w_y + 1409024;      // 524288
  float* w_s    = w_y + 1933312;      // 1048576
  float* w_k    = w_y + 2981888;      // 1048576
  float* w_q    = w_y + 4030464;      // 1048576
  float* w_v    = w_y + 5079040;      // 1048576
  float* w_sc   = w_y + 6127616;      // 524288
  float* w_scT  = w_y + 6651904;      // 524288
  float* w_f    = w_y + 7176192;      // 1048576
  float* w_g    = w_y + 8224768;      // 1048576
  float* w_outs = w_y + 9273344;      // 2097152
  float* w_s2   = w_y + 11370496;     // 1048576 (ends 12419072 < 18874368)

  prep_w1_kernel<<<576, 256, 0, stream>>>(conv1_w, (uint4*)w_W1h, (uint4*)w_W1l);
  prep_w2_kernel<<<16, 256, 0, stream>>>(conv2_w, (uint4*)w_W2h, (uint4*)w_W2l);
  prep_bn_kernel<<<1, 256, 0, stream>>>(bn1_g, bn1_b, bn1_m, bn1_v, w_s1, w_t1);

  conv_mfma_kernel<9, 512, 2, true><<<1152, 256, 0, stream>>>(
      x, (const uint4*)w_W1h, (const uint4*)w_W1l, w_s1, w_t1, w_y);
  conv_mfma_kernel<1, 256, 1, false><<<576, 256, 0, stream>>>(
      w_y, (const uint4*)w_W2h, (const uint4*)w_W2l, w_s1, w_t1, w_x2);

  xave_kernel<<<4096, 256, 0, stream>>>(w_x2, w_xave);
  xan_kernel<<<32, 128, 0, stream>>>(w_xave, w_xan);
  cos_kernel<<<288, 256, 0, stream>>>(w_x2, w_xan, w_cos);
  lbp_kernel<<<32, 256, 0, stream>>>(w_cos, w_code, w_qlv);
  quant_kernel<<<32, 256, 0, stream>>>(w_code, w_qlv, w_quant);
  sta_kernel<<<32, 128, 0, stream>>>(w_quant, w_sta);
  h1_kernel<<<1024, 256, 0, stream>>>(f1_w, w_qlv, w_sta, w_h1);
  gemm_w_kernel<<<512, 256, 0, stream>>>(f2_w, w_h1, w_h2, 64, 128, N_IMG * 32 * 128, 1,
                                         f2_g, f2_b, f2_m, f2_v);
  concat_kernel<<<4096, 256, 0, stream>>>(w_h2, w_xave, w_s);
  gemm_w_kernel<<<1024, 256, 0, stream>>>(out1_w, w_s, w_s2, 256, 256, N_IMG * 64 * 128, 1,
                                          out1_g, out1_b, out1_m, out1_v);
  gemm_w_kernel<<<1024, 256, 0, stream>>>(k_w, w_s2, w_k, 256, 256, N_IMG * 64 * 128, 0,
                                          nullptr, nullptr, nullptr, nullptr);
  gemm_w_kernel<<<1024, 256, 0, stream>>>(q_w, w_s2, w_q, 256, 256, N_IMG * 64 * 128, 0,
                                          nullptr, nullptr, nullptr, nullptr);
  gemm_w_kernel<<<1024, 256, 0, stream>>>(v_w, w_s2, w_v, 256, 256, N_IMG * 64 * 128, 0,
                                          nullptr, nullptr, nullptr, nullptr);
  attn_sc_kernel<<<512, 256, 0, stream>>>(w_k, w_q, w_sc);
  softmax_kernel<<<4096, 128, 0, stream>>>(w_sc);
  transpose_sc_kernel<<<2048, 256, 0, stream>>>(w_sc, w_scT);
  attn_f_kernel<<<1024, 256, 0, stream>>>(w_v, w_scT, w_f);
  gemm_w_kernel<<<1024, 256, 0, stream>>>(out_w, w_f, w_g, 256, 256, N_IMG * 64 * 128, 1,
                                          out_g, out_b, out_m, out_v);
  final_kernel<<<2048, 256, 0, stream>>>(w_g, w_quant, w_outs);
  resize_kernel<<<73728, 256, 0, stream>>>(w_outs, dout);
}

// Round 3
// 1583.860 us; speedup vs baseline: 2.3753x; 1.1856x over previous
//
#include <hip/hip_runtime.h>
#include <math.h>

#define N_IMG 32
#define P2304 2304
#define CIN 512
#define CMID 256
#define C2 128
#define LEV 128

typedef _Float16 half8 __attribute__((ext_vector_type(8)));
typedef float f32x16 __attribute__((ext_vector_type(16)));

// ---------------- wave/block reduction helpers (wave = 64) ----------------
__device__ __forceinline__ float wredSum(float v){
#pragma unroll
  for (int o = 32; o > 0; o >>= 1) v += __shfl_down(v, o, 64);
  return v;
}
__device__ __forceinline__ float wredMax(float v){
#pragma unroll
  for (int o = 32; o > 0; o >>= 1) v = fmaxf(v, __shfl_down(v, o, 64));
  return v;
}
__device__ __forceinline__ float wredMin(float v){
#pragma unroll
  for (int o = 32; o > 0; o >>= 1) v = fminf(v, __shfl_down(v, o, 64));
  return v;
}

// ---------------- weight prepack: split f32 -> (hi, lo*2^11) f16 frags ----
// Fragment order: frag index fi = ((kt*COTN + cot)*4 + c32)*64 + lam,
// holding 8 f16: element j is W[co = cot*128 + c32*32 + (lam&31)]
//                             [k  = kt*16 + (lam>>5)*8 + j]
__global__ void prep_w1_kernel(const float* __restrict__ w1,
                               uint4* __restrict__ Wh, uint4* __restrict__ Wl){
  int fid = blockIdx.x * 256 + threadIdx.x;     // 147456 frags
  int lam = fid & 63;
  int c32 = (fid >> 6) & 3;
  int cot = (fid >> 8) & 1;
  int kt  = fid >> 9;                           // 0..287
  int co = cot * 128 + c32 * 32 + (lam & 31);
  half8 vh, vl;
#pragma unroll
  for (int j = 0; j < 8; ++j){
    int k = kt * 16 + ((lam >> 5) << 3) + j;    // 0..4607
    int r = k >> 9;                             // tap
    int ci = k & 511;
    float v = w1[co * (CIN * 9) + ci * 9 + r];
    _Float16 h = (_Float16)v;
    vh[j] = h;
    vl[j] = (_Float16)((v - (float)h) * 2048.0f);
  }
  Wh[fid] = *(uint4*)&vh;
  Wl[fid] = *(uint4*)&vl;
}

__global__ void prep_w2_kernel(const float* __restrict__ w2,
                               uint4* __restrict__ Wh, uint4* __restrict__ Wl){
  int fid = blockIdx.x * 256 + threadIdx.x;     // 4096 frags
  int lam = fid & 63;
  int c32 = (fid >> 6) & 3;
  int kt  = fid >> 8;                           // 0..15
  int co = c32 * 32 + (lam & 31);
  half8 vh, vl;
#pragma unroll
  for (int j = 0; j < 8; ++j){
    int k = kt * 16 + ((lam >> 5) << 3) + j;    // 0..255
    float v = w2[co * CMID + k];
    _Float16 h = (_Float16)v;
    vh[j] = h;
    vl[j] = (_Float16)((v - (float)h) * 2048.0f);
  }
  Wh[fid] = *(uint4*)&vh;
  Wl[fid] = *(uint4*)&vl;
}

// s1 = g/sqrt(v+eps), t1 = b - m*s1  (bn folded to y*s1 + t1)
__global__ void prep_bn_kernel(const float* __restrict__ g1, const float* __restrict__ b1,
                               const float* __restrict__ m1, const float* __restrict__ v1,
                               float* __restrict__ s1, float* __restrict__ t1){
  int c = threadIdx.x;  // 256
  float s = g1[c] * (1.0f / sqrtf(v1[c] + 1e-5f));
  s1[c] = s;
  t1[c] = b1[c] - m1[c] * s;
}

// ---------------- split-f16 MFMA conv (3x3 SAME or 1x1) -------------------
// GEMM: M = COTN*128 (co), N = 2304 (p), K = R*CPT. Block tile 128co x 128p,
// 4 waves, each wave 64x64 via 2x2 mfma_32x32x16 tiles, dual accumulators
// (hh and scaled cross terms). Software-pipelined: global loads for kt+1 are
// issued right after the 2nd barrier so 12 MFMA (384 wave-cyc) cover their
// latency; consumers (convert+LDS store) sit at the top of the next iter.
template<int R, int CPT, int COTN, bool BN>
__global__ __launch_bounds__(256, 2) void conv_mfma_kernel(
    const float* __restrict__ in, const uint4* __restrict__ Wh, const uint4* __restrict__ Wl,
    const float* __restrict__ s1, const float* __restrict__ t1, float* __restrict__ out)
{
  __shared__ _Float16 Ah[2048], Al[2048], Bh[2048], Bl[2048];
  const int t = threadIdx.x;
  const int lam = t & 63;
  const int g = t >> 6;          // wave id; also c32 group (A stage) / p32 group (B stage)

  int n, pt_blk, cot;
  if (COTN == 2){
    // XCD-aware swizzle: blockIdx%8 -> XCD; give each XCD a private n-range.
    int xcd = blockIdx.x & 7;
    int rest = blockIdx.x >> 3;  // 0..143
    n = xcd * 4 + rest / 36;
    int inner = rest % 36;
    pt_blk = inner % 18;
    cot = inner / 18;
  } else {
    pt_blk = blockIdx.x % 18;
    cot = 0;
    n = blockIdx.x / 18;
  }
  const int pbase = pt_blk * 128;
  const int cobase = cot * 128;

  // B staging coords (fixed per thread)
  const int khi = lam >> 5;                    // 0/1: k-half of fragment
  const int pp = (g << 5) + (lam & 31);        // 0..127 within p-tile
  const int p = pbase + pp;
  const int ph = p / 48, pw = p - ph * 48;
  const float* in_n = in + (size_t)n * CPT * P2304;

  const int KTPR = CPT / 16;
  const int KT = R * KTPR;

  f32x16 acc_hh[2][2], acc_x[2][2];
#pragma unroll
  for (int a = 0; a < 2; ++a)
#pragma unroll
    for (int b = 0; b < 2; ++b){
#pragma unroll
      for (int e = 0; e < 16; ++e){ acc_hh[a][b][e] = 0.f; acc_x[a][b][e] = 0.f; }
    }

  // ---- prefetch state (depth-1 software pipeline) ----
  uint4 rAh, rAl;
  float rB[8];

#define LOAD_AB(KTV)                                                          \
  {                                                                           \
    int kt_ = (KTV);                                                          \
    int fi = ((kt_ * COTN + cot) * 4 + g) * 64 + lam;                         \
    rAh = Wh[fi];                                                             \
    rAl = Wl[fi];                                                             \
    int r_ = kt_ / KTPR;                                                      \
    int it_ = kt_ - r_ * KTPR;                                                \
    int dh_ = (R == 1) ? 0 : (r_ / 3 - 1);                                    \
    int dw_ = (R == 1) ? 0 : (r_ - (r_ / 3) * 3 - 1);                         \
    int hh_ = ph + dh_, ww_ = pw + dw_;                                       \
    bool valid_ = ((unsigned)hh_ < 48u) & ((unsigned)ww_ < 48u);              \
    const float* src_ = in_n + (valid_ ? (hh_ * 48 + ww_) : 0)                \
                        + (size_t)((khi << 3) + (it_ << 4)) * P2304;          \
    _Pragma("unroll")                                                         \
    for (int j = 0; j < 8; ++j) rB[j] = valid_ ? src_[j * P2304] : 0.0f;      \
  }

  LOAD_AB(0);

  for (int kt = 0; kt < KT; ++kt){
    // convert prefetched B (f32 -> hi/lo f16); forces the vmcnt wait here,
    // which was covered by the previous iteration's MFMA block.
    half8 vh, vl;
#pragma unroll
    for (int j = 0; j < 8; ++j){
      float v = rB[j];
      _Float16 h = (_Float16)v;
      vh[j] = h;
      vl[j] = (_Float16)((v - (float)h) * 2048.0f);
    }
    uint4 sAh = rAh, sAl = rAl;
    __syncthreads();   // previous iteration's LDS readers done
    *(uint4*)&Ah[t * 8] = sAh;
    *(uint4*)&Al[t * 8] = sAl;
    *(half8*)&Bh[t * 8] = vh;
    *(half8*)&Bl[t * 8] = vl;
    __syncthreads();
    if (kt + 1 < KT) LOAD_AB(kt + 1);   // issue next loads; consumed next iter

    // fragments for this wave's 64x64 quadrant
    const int ct0 = (g & 1) * 2, pt0 = (g >> 1) * 2;
    half8 fAh[2], fAl[2], fBh[2], fBl[2];
#pragma unroll
    for (int a = 0; a < 2; ++a){
      fAh[a] = *(half8*)&Ah[((ct0 + a) * 64 + lam) * 8];
      fAl[a] = *(half8*)&Al[((ct0 + a) * 64 + lam) * 8];
      fBh[a] = *(half8*)&Bh[((pt0 + a) * 64 + lam) * 8];
      fBl[a] = *(half8*)&Bl[((pt0 + a) * 64 + lam) * 8];
    }
#pragma unroll
    for (int a = 0; a < 2; ++a)
#pragma unroll
      for (int b = 0; b < 2; ++b){
        acc_hh[a][b] = __builtin_amdgcn_mfma_f32_32x32x16_f16(fAh[a], fBh[b], acc_hh[a][b], 0, 0, 0);
        acc_x[a][b]  = __builtin_amdgcn_mfma_f32_32x32x16_f16(fAh[a], fBl[b], acc_x[a][b], 0, 0, 0);
        acc_x[a][b]  = __builtin_amdgcn_mfma_f32_32x32x16_f16(fAl[a], fBh[b], acc_x[a][b], 0, 0, 0);
      }
  }
#undef LOAD_AB

  // epilogue: combine hi/lo passes, optional bn+leaky, store f32
  const int M = COTN * 128;
#pragma unroll
  for (int a = 0; a < 2; ++a){
    const int ctile = (g & 1) * 2 + a;
#pragma unroll
    for (int b = 0; b < 2; ++b){
      const int ptile = (g >> 1) * 2 + b;
      const int pg = pbase + ptile * 32 + (lam & 31);
#pragma unroll
      for (int rg = 0; rg < 16; ++rg){
        const int row = (rg & 3) + 8 * (rg >> 2) + 4 * (lam >> 5);
        const int co = cobase + ctile * 32 + row;
        float val = acc_hh[a][b][rg] + acc_x[a][b][rg] * (1.0f / 2048.0f);
        if (BN){
          val = val * s1[co] + t1[co];
          val = val > 0.f ? val : 0.01f * val;
        }
        out[((size_t)n * M + co) * P2304 + pg] = val;
      }
    }
  }
}

// ---------------- x_ave (mean over 2304 positions per (n,c)) ----------------
__global__ void xave_kernel(const float* __restrict__ x2, float* __restrict__ xave){
  __shared__ float red[4];
  int nc = blockIdx.x, t = threadIdx.x;
  const float* row = x2 + nc * P2304;
  float s = 0.f;
#pragma unroll
  for (int i = 0; i < 9; i++) s += row[t + 256 * i];
  float w = wredSum(s);
  if ((t & 63) == 0) red[t >> 6] = w;
  __syncthreads();
  if (t == 0) xave[nc] = (red[0] + red[1] + red[2] + red[3]) * (1.0f / 2304.0f);
}

// l2-normalize x_ave over channels
__global__ void xan_kernel(const float* __restrict__ xave, float* __restrict__ xan){
  __shared__ float red[2];
  int n = blockIdx.x, t = threadIdx.x; // 128 threads
  float v = xave[n * 128 + t];
  float w = wredSum(v * v);
  if ((t & 63) == 0) red[t >> 6] = w;
  __syncthreads();
  float norm = fmaxf(sqrtf(red[0] + red[1]), 1e-12f);
  xan[n * 128 + t] = v / norm;
}

// cos[n,p] = <xan, x2hat[:,p]>
__global__ void cos_kernel(const float* __restrict__ x2, const float* __restrict__ xan,
                           float* __restrict__ cosb){
  int idx = blockIdx.x * 256 + threadIdx.x;
  if (idx >= N_IMG * P2304) return;
  int n = idx / P2304;
  int p = idx - n * P2304;
  const float* xp = x2 + n * C2 * P2304 + p;
  const float* an = xan + n * 128;
  float dot = 0.f, ss = 0.f;
  for (int c = 0; c < 128; c++){
    float v = xp[c * P2304];
    dot += an[c] * v;
    ss  += v * v;
  }
  cosb[idx] = dot / fmaxf(sqrtf(ss), 1e-12f);
}

// ---------------- LBP code + normalization + qlv ----------------
__global__ void lbp_kernel(const float* __restrict__ cosb, float* __restrict__ code,
                           float* __restrict__ qlv){
  __shared__ float red[4];
  int n = blockIdx.x;
  int l = threadIdx.x;           // 256 positions, l = ir*16+ic
  int ir = l >> 4, ic = l & 15;
  const float* cn = cosb + n * P2304;
  float cs4 = cn[(16 + ir) * 48 + (16 + ic)];
  const float wts[9] = {1.f, 2.f, 4.f, 8.f, 0.f, 16.f, 32.f, 64.f, 128.f};
  float codev = 0.f;
#pragma unroll
  for (int j = 0; j < 9; j++){
    int jr = j / 3, jc = j - 3 * (j / 3);
    float vv = cn[(jr * 16 + ir) * 48 + (jc * 16 + ic)];
    if (vv > cs4) codev += wts[j];
  }
  float w;
  w = wredMin(codev);
  if ((l & 63) == 0) red[l >> 6] = w;
  __syncthreads();
  float mn = fminf(fminf(red[0], red[1]), fminf(red[2], red[3]));
  __syncthreads();
  w = wredMax(codev);
  if ((l & 63) == 0) red[l >> 6] = w;
  __syncthreads();
  float mx = fmaxf(fmaxf(red[0], red[1]), fmaxf(red[2], red[3]));
  __syncthreads();
  float cd = (codev - mn) / (mx - mn);
  w = wredMin(cd);
  if ((l & 63) == 0) red[l >> 6] = w;
  __syncthreads();
  float cmin = fminf(fminf(red[0], red[1]), fminf(red[2], red[3]));
  __syncthreads();
  w = wredMax(cd);
  if ((l & 63) == 0) red[l >> 6] = w;
  __syncthreads();
  float cmax = fmaxf(fmaxf(red[0], red[1]), fmaxf(red[2], red[3]));
  code[n * 256 + l] = cd;
  if (l < 128){
    float tmp = (float)(2 * l + 1) * (1.0f / 256.0f);
    qlv[n * 128 + l] = tmp * (cmax - cmin) + cmin;
  }
}

// quantT[n][lev][p] = thresholded soft-assignment (transposed for coalescing)
__global__ void quant_kernel(const float* __restrict__ code, const float* __restrict__ qlv,
                             float* __restrict__ quantT){
  __shared__ float cs[256];
  __shared__ float qs[128];
  int n = blockIdx.x, t = threadIdx.x;
  cs[t] = code[n * 256 + t];
  if (t < 128) qs[t] = qlv[n * 128 + t];
  __syncthreads();
  float thr = 1.0f - (qs[1] - qs[0]);
  float* dst = quantT + n * LEV * 256;
#pragma unroll 4
  for (int i = 0; i < 128; i++){
    int v = t + 256 * i;
    int lv = v >> 8;
    int p = v & 255;
    float qq = 1.0f - fabsf(qs[lv] - cs[p]);
    dst[v] = (qq > thr) ? qq : 0.f;
  }
}

// sta[n][i] = sum_p quant / total
__global__ void sta_kernel(const float* __restrict__ quantT, float* __restrict__ sta){
  __shared__ float red[2];
  int n = blockIdx.x, i = threadIdx.x; // 128 threads
  const float* qr = quantT + (n * LEV + i) * 256;
  float s = 0.f;
  for (int p = 0; p < 256; p++) s += qr[p];
  float w = wredSum(s);
  if ((i & 63) == 0) red[i >> 6] = w;
  __syncthreads();
  float tot = red[0] + red[1];
  sta[n * 128 + i] = s / tot;
}

// h1 = leaky(f1_w @ [qlv; sta])
__global__ void h1_kernel(const float* __restrict__ f1w, const float* __restrict__ qlv,
                          const float* __restrict__ sta, float* __restrict__ h1){
  int idx = blockIdx.x * 256 + threadIdx.x;
  if (idx >= N_IMG * 64 * 128) return;
  int l = idx & 127;
  int n = idx >> 13;
  int o = (idx >> 7) & 63;
  float a = f1w[o * 2] * qlv[n * 128 + l] + f1w[o * 2 + 1] * sta[n * 128 + l];
  h1[idx] = a > 0.f ? a : 0.01f * a;
}

// generic per-image "W @ B" with optional bn+relu: C[n,o,l] = act(sum_c Wm[o,c]*B[n,c,l])
__global__ void gemm_w_kernel(const float* __restrict__ Wm, const float* __restrict__ B,
                              float* __restrict__ Cout, int Cdim, int O, int total, int mode,
                              const float* __restrict__ g, const float* __restrict__ bb,
                              const float* __restrict__ mm, const float* __restrict__ vv){
  int idx = blockIdx.x * 256 + threadIdx.x;
  if (idx >= total) return;
  int per_n = (O >> 2) << 7;
  int n = idx / per_n;
  int rem = idx - n * per_n;
  int o0 = (rem >> 7) << 2;
  int l = rem & 127;
  const float* Bn = B + (n * Cdim) * 128 + l;
  const float* w0 = Wm + (o0 + 0) * Cdim;
  const float* w1 = Wm + (o0 + 1) * Cdim;
  const float* w2 = Wm + (o0 + 2) * Cdim;
  const float* w3 = Wm + (o0 + 3) * Cdim;
  float a0 = 0, a1 = 0, a2 = 0, a3 = 0;
  for (int c = 0; c < Cdim; c++){
    float bv = Bn[c * 128];
    a0 += w0[c] * bv; a1 += w1[c] * bv; a2 += w2[c] * bv; a3 += w3[c] * bv;
  }
  float av[4] = {a0, a1, a2, a3};
#pragma unroll
  for (int j = 0; j < 4; j++){
    int o = o0 + j;
    float val = av[j];
    if (mode == 1){
      float s = g[o] * (1.0f / sqrtf(vv[o] + 1e-5f));
      val = (val - mm[o]) * s + bb[o];
      val = fmaxf(val, 0.f);
    }
    Cout[(n * O + o) * 128 + l] = val;
  }
}

// s = concat([h2, broadcast(x_ave)], channel dim)
__global__ void concat_kernel(const float* __restrict__ h2, const float* __restrict__ xave,
                              float* __restrict__ s){
  int idx = blockIdx.x * 256 + threadIdx.x;
  if (idx >= N_IMG * 256 * 128) return;
  int l = idx & 127;
  int c = (idx >> 7) & 255;
  int n = idx >> 15;
  s[idx] = (c < 128) ? h2[(n * 128 + c) * 128 + l] : xave[n * 128 + (c - 128)];
}

// sc[n,l,m] = sum_c k[n,c,l]*q[n,c,m]
__global__ void attn_sc_kernel(const float* __restrict__ k, const float* __restrict__ q,
                               float* __restrict__ sc){
  int idx = blockIdx.x * 256 + threadIdx.x;
  if (idx >= N_IMG * 32 * 128) return;
  int m = idx & 127;
  int l0 = ((idx >> 7) & 31) << 2;
  int n = idx >> 12;
  const float* kn = k + n * 256 * 128;
  const float* qn = q + n * 256 * 128 + m;
  float a0 = 0, a1 = 0, a2 = 0, a3 = 0;
  for (int c = 0; c < 256; c++){
    float qv = qn[c * 128];
    const float* kr = kn + c * 128 + l0;
    a0 += kr[0] * qv; a1 += kr[1] * qv; a2 += kr[2] * qv; a3 += kr[3] * qv;
  }
  float* dst = sc + (n * 128 + l0) * 128 + m;
  dst[0] = a0; dst[128] = a1; dst[256] = a2; dst[384] = a3;
}

__global__ void softmax_kernel(float* __restrict__ sc){
  __shared__ float red[2];
  int row = blockIdx.x;
  int t = threadIdx.x; // 128
  float v = sc[row * 128 + t];
  float w = wredMax(v);
  if ((t & 63) == 0) red[t >> 6] = w;
  __syncthreads();
  float mx = fmaxf(red[0], red[1]);
  float e = expf(v - mx);
  float s = wredSum(e);
  __syncthreads();
  if ((t & 63) == 0) red[t >> 6] = s;
  __syncthreads();
  sc[row * 128 + t] = e / (red[0] + red[1]);
}

__global__ void transpose_sc_kernel(const float* __restrict__ sc, float* __restrict__ scT){
  int idx = blockIdx.x * 256 + threadIdx.x;
  if (idx >= N_IMG * 128 * 128) return;
  int l = idx & 127;
  int m = (idx >> 7) & 127;
  int n = idx >> 14;
  scT[idx] = sc[(n * 128 + l) * 128 + m];
}

// f[n,c,l] = sum_m v[n,c,m]*scT[n,m,l]
__global__ void attn_f_kernel(const float* __restrict__ vb, const float* __restrict__ scT,
                              float* __restrict__ f){
  int idx = blockIdx.x * 256 + threadIdx.x;
  if (idx >= N_IMG * 64 * 128) return;
  int l = idx & 127;
  int c0 = ((idx >> 7) & 63) << 2;
  int n = idx >> 13;
  const float* vn = vb + (n * 256 + c0) * 128;
  const float* sn = scT + n * 128 * 128 + l;
  float a0 = 0, a1 = 0, a2 = 0, a3 = 0;
  for (int m = 0; m < 128; m++){
    float sv = sn[m * 128];
    a0 += vn[m] * sv; a1 += vn[128 + m] * sv; a2 += vn[256 + m] * sv; a3 += vn[384 + m] * sv;
  }
  float* dst = f + (n * 256 + c0) * 128 + l;
  dst[0] = a0; dst[128] = a1; dst[256] = a2; dst[384] = a3;
}

// outs[n,c,p] = sum_lev g[n,c,lev]*quantT[n,lev,p]
__global__ void final_kernel(const float* __restrict__ g, const float* __restrict__ quantT,
                             float* __restrict__ outs){
  int idx = blockIdx.x * 256 + threadIdx.x;
  if (idx >= N_IMG * 64 * 256) return;
  int p = idx & 255;
  int c0 = ((idx >> 8) & 63) << 2;
  int n = idx >> 14;
  const float* gn = g + (n * 256 + c0) * 128;
  const float* qn = quantT + (n * LEV) * 256 + p;
  float a0 = 0, a1 = 0, a2 = 0, a3 = 0;
  for (int lv = 0; lv < 128; lv++){
    float qv = qn[lv * 256];
    a0 += gn[lv] * qv; a1 += gn[128 + lv] * qv; a2 += gn[256 + lv] * qv; a3 += gn[384 + lv] * qv;
  }
  float* dst = outs + (n * 256 + c0) * 256 + p;
  dst[0] = a0; dst[256] = a1; dst[512] = a2; dst[768] = a3;
}

// bilinear 16x16 -> 48x48 (align_corners-style linspace(0,15,48))
__global__ void resize_kernel(const float* __restrict__ outs, float* __restrict__ dout){
  int idx = blockIdx.x * 256 + threadIdx.x;
  if (idx >= N_IMG * 256 * P2304) return;
  int ow = idx % 48;
  int tmp = idx / 48;
  int oh = tmp % 48;
  int nc = tmp / 48;
  const float* src = outs + nc * 256;
  float fy = oh * (15.0f / 47.0f);
  float fx = ow * (15.0f / 47.0f);
  int y0 = (int)fy;
  int x0 = (int)fx;
  int y1 = min(y0 + 1, 15);
  int x1 = min(x0 + 1, 15);
  float wy = fy - (float)y0;
  float wx = fx - (float)x0;
  float v00 = src[y0 * 16 + x0], v01 = src[y0 * 16 + x1];
  float v10 = src[y1 * 16 + x0], v11 = src[y1 * 16 + x1];
  dout[idx] = v00 * (1.f - wy) * (1.f - wx) + v01 * (1.f - wy) * wx
            + v10 * wy * (1.f - wx) + v11 * wy * wx;
}

// ---------------- launcher ----------------
extern "C" void kernel_launch(void* const* d_in, const int* in_sizes, int n_in,
                              void* d_out, int out_size, void* d_ws, size_t ws_size,
                              hipStream_t stream)
{
  const float* x       = (const float*)d_in[0];
  const float* conv1_w = (const float*)d_in[1];
  const float* bn1_g   = (const float*)d_in[2];
  const float* bn1_b   = (const float*)d_in[3];
  const float* bn1_m   = (const float*)d_in[4];
  const float* bn1_v   = (const float*)d_in[5];
  const float* conv2_w = (const float*)d_in[6];
  const float* f1_w    = (const float*)d_in[7];
  const float* f2_w    = (const float*)d_in[8];
  const float* f2_g    = (const float*)d_in[9];
  const float* f2_b    = (const float*)d_in[10];
  const float* f2_m    = (const float*)d_in[11];
  const float* f2_v    = (const float*)d_in[12];
  const float* out1_w  = (const float*)d_in[13];
  const float* out1_g  = (const float*)d_in[14];
  const float* out1_b  = (const float*)d_in[15];
  const float* out1_m  = (const float*)d_in[16];
  const float* out1_v  = (const float*)d_in[17];
  const float* k_w     = (const float*)d_in[18];
  const float* q_w     = (const float*)d_in[19];
  const float* v_w     = (const float*)d_in[20];
  const float* out_w   = (const float*)d_in[21];
  const float* out_g   = (const float*)d_in[22];
  const float* out_b   = (const float*)d_in[23];
  const float* out_m   = (const float*)d_in[24];
  const float* out_v   = (const float*)d_in[25];

  float* ws = (float*)d_ws;
  float* dout = (float*)d_out;

  // large buffers
  float* w_y   = ws;                  // 18874368 f (y: 32x256x2304) -- dead after conv2
  float* w_x2  = ws + 18874368;       // 9437184 f
  float* w_W1h = ws + 28311552;       // 589824 f-slots = 1179648 f16 (packed frags)
  float* w_W1l = ws + 28901376;       // 589824
  float* w_W2h = ws + 29491200;       // 16384 f-slots = 32768 f16
  float* w_W2l = ws + 29507584;       // 16384
  float* w_s1  = ws + 29523968;       // 256
  float* w_t1  = ws + 29524224;       // 256  => total 29524480 f = 118.1 MB
  // small buffers reuse the y region (only written after conv2 consumed y)
  float* w_xave = w_y + 0;            // 4096
  float* w_xan  = w_y + 4096;         // 4096
  float* w_cos  = w_y + 8192;         // 73728
  float* w_code = w_y + 81920;        // 8192
  float* w_qlv  = w_y + 90112;        // 4096
  float* w_sta  = w_y + 94208;        // 4096
  float* w_quant= w_y + 98304;        // 1048576 (quantT [n][lev][p])
  float* w_h1   = w_y + 1146880;      // 262144
  float* w_h2   = w_y + 1409024;      // 524288
  float* w_s    = w_y + 1933312;      // 1048576
  float* w_k    = w_y + 2981888;      // 1048576
  float* w_q    = w_y + 4030464;      // 1048576
  float* w_v    = w_y + 5079040;      // 1048576
  float* w_sc   = w_y + 6127616;      // 524288
  float* w_scT  = w_y + 6651904;      // 524288
  float* w_f    = w_y + 7176192;      // 1048576
  float* w_g    = w_y + 8224768;      // 1048576
  float* w_outs = w_y + 9273344;      // 2097152
  float* w_s2   = w_y + 11370496;     // 1048576 (ends 12419072 < 18874368)

  prep_w1_kernel<<<576, 256, 0, stream>>>(conv1_w, (uint4*)w_W1h, (uint4*)w_W1l);
  prep_w2_kernel<<<16, 256, 0, stream>>>(conv2_w, (uint4*)w_W2h, (uint4*)w_W2l);
  prep_bn_kernel<<<1, 256, 0, stream>>>(bn1_g, bn1_b, bn1_m, bn1_v, w_s1, w_t1);

  conv_mfma_kernel<9, 512, 2, true><<<1152, 256, 0, stream>>>(
      x, (const uint4*)w_W1h, (const uint4*)w_W1l, w_s1, w_t1, w_y);
  conv_mfma_kernel<1, 256, 1, false><<<576, 256, 0, stream>>>(
      w_y, (const uint4*)w_W2h, (const uint4*)w_W2l, w_s1, w_t1, w_x2);

  xave_kernel<<<4096, 256, 0, stream>>>(w_x2, w_xave);
  xan_kernel<<<32, 128, 0, stream>>>(w_xave, w_xan);
  cos_kernel<<<288, 256, 0, stream>>>(w_x2, w_xan, w_cos);
  lbp_kernel<<<32, 256, 0, stream>>>(w_cos, w_code, w_qlv);
  quant_kernel<<<32, 256, 0, stream>>>(w_code, w_qlv, w_quant);
  sta_kernel<<<32, 128, 0, stream>>>(w_quant, w_sta);
  h1_kernel<<<1024, 256, 0, stream>>>(f1_w, w_qlv, w_sta, w_h1);
  gemm_w_kernel<<<512, 256, 0, stream>>>(f2_w, w_h1, w_h2, 64, 128, N_IMG * 32 * 128, 1,
                                         f2_g, f2_b, f2_m, f2_v);
  concat_kernel<<<4096, 256, 0, stream>>>(w_h2, w_xave, w_s);
  gemm_w_kernel<<<1024, 256, 0, stream>>>(out1_w, w_s, w_s2, 256, 256, N_IMG * 64 * 128, 1,
                                          out1_g, out1_b, out1_m, out1_v);
  gemm_w_kernel<<<1024, 256, 0, stream>>>(k_w, w_s2, w_k, 256, 256, N_IMG * 64 * 128, 0,
                                          nullptr, nullptr, nullptr, nullptr);
  gemm_w_kernel<<<1024, 256, 0, stream>>>(q_w, w_s2, w_q, 256, 256, N_IMG * 64 * 128, 0,
                                          nullptr, nullptr, nullptr, nullptr);
  gemm_w_kernel<<<1024, 256, 0, stream>>>(v_w, w_s2, w_v, 256, 256, N_IMG * 64 * 128, 0,
                                          nullptr, nullptr, nullptr, nullptr);
  attn_sc_kernel<<<512, 256, 0, stream>>>(w_k, w_q, w_sc);
  softmax_kernel<<<4096, 128, 0, stream>>>(w_sc);
  transpose_sc_kernel<<<2048, 256, 0, stream>>>(w_sc, w_scT);
  attn_f_kernel<<<1024, 256, 0, stream>>>(w_v, w_scT, w_f);
  gemm_w_kernel<<<1024, 256, 0, stream>>>(out_w, w_f, w_g, 256, 256, N_IMG * 64 * 128, 1,
                                          out_g, out_b, out_m, out_v);
  final_kernel<<<2048, 256, 0, stream>>>(w_g, w_quant, w_outs);
  resize_kernel<<<73728, 256, 0, stream>>>(w_outs, dout);
}

// Round 4
// 1511.106 us; speedup vs baseline: 2.4896x; 1.0481x over previous
//
#include <hip/hip_runtime.h>
#include <math.h>

#define N_IMG 32
#define P2304 2304
#define CIN 512
#define CMID 256
#define C2 128
#define LEV 128

typedef _Float16 half8 __attribute__((ext_vector_type(8)));
typedef float f32x16 __attribute__((ext_vector_type(16)));

// ---------------- wave/block reduction helpers (wave = 64) ----------------
__device__ __forceinline__ float wredSum(float v){
#pragma unroll
  for (int o = 32; o > 0; o >>= 1) v += __shfl_down(v, o, 64);
  return v;
}
__device__ __forceinline__ float wredMax(float v){
#pragma unroll
  for (int o = 32; o > 0; o >>= 1) v = fmaxf(v, __shfl_down(v, o, 64));
  return v;
}
__device__ __forceinline__ float wredMin(float v){
#pragma unroll
  for (int o = 32; o > 0; o >>= 1) v = fminf(v, __shfl_down(v, o, 64));
  return v;
}

// ---------------- weight prepack: split f32 -> (hi, lo*2^11) f16 frags ----
// Fragment order: frag index fi = ((kt*COTN + cot)*4 + c32)*64 + lam,
// holding 8 f16: element j is W[co = cot*128 + c32*32 + (lam&31)]
//                             [k  = kt*16 + (lam>>5)*8 + j]
__global__ void prep_w1_kernel(const float* __restrict__ w1,
                               uint4* __restrict__ Wh, uint4* __restrict__ Wl){
  int fid = blockIdx.x * 256 + threadIdx.x;     // 147456 frags
  int lam = fid & 63;
  int c32 = (fid >> 6) & 3;
  int cot = (fid >> 8) & 1;
  int kt  = fid >> 9;                           // 0..287
  int co = cot * 128 + c32 * 32 + (lam & 31);
  half8 vh, vl;
#pragma unroll
  for (int j = 0; j < 8; ++j){
    int k = kt * 16 + ((lam >> 5) << 3) + j;    // 0..4607
    int r = k >> 9;                             // tap
    int ci = k & 511;
    float v = w1[co * (CIN * 9) + ci * 9 + r];
    _Float16 h = (_Float16)v;
    vh[j] = h;
    vl[j] = (_Float16)((v - (float)h) * 2048.0f);
  }
  Wh[fid] = *(uint4*)&vh;
  Wl[fid] = *(uint4*)&vl;
}

__global__ void prep_w2_kernel(const float* __restrict__ w2,
                               uint4* __restrict__ Wh, uint4* __restrict__ Wl){
  int fid = blockIdx.x * 256 + threadIdx.x;     // 4096 frags
  int lam = fid & 63;
  int c32 = (fid >> 6) & 3;
  int kt  = fid >> 8;                           // 0..15
  int co = c32 * 32 + (lam & 31);
  half8 vh, vl;
#pragma unroll
  for (int j = 0; j < 8; ++j){
    int k = kt * 16 + ((lam >> 5) << 3) + j;    // 0..255
    float v = w2[co * CMID + k];
    _Float16 h = (_Float16)v;
    vh[j] = h;
    vl[j] = (_Float16)((v - (float)h) * 2048.0f);
  }
  Wh[fid] = *(uint4*)&vh;
  Wl[fid] = *(uint4*)&vl;
}

// s1 = g/sqrt(v+eps), t1 = b - m*s1  (bn folded to y*s1 + t1)
__global__ void prep_bn_kernel(const float* __restrict__ g1, const float* __restrict__ b1,
                               const float* __restrict__ m1, const float* __restrict__ v1,
                               float* __restrict__ s1, float* __restrict__ t1){
  int c = threadIdx.x;  // 256
  float s = g1[c] * (1.0f / sqrtf(v1[c] + 1e-5f));
  s1[c] = s;
  t1[c] = b1[c] - m1[c] * s;
}

// ---------------- split-f16 MFMA conv (3x3 SAME or 1x1) -------------------
// GEMM: M = COTN*128 (co), N = 2304 (p), K = R*CPT. Block tile 128co x 128p,
// 4 waves, each wave 64x64 via 2x2 mfma_32x32x16 tiles, dual accumulators.
// Pipeline: BK=32 stages, double-buffered LDS (64 KB), ONE barrier per stage.
// Global loads for stage s+1 issued at top of stage s (unconditional, clamped
// addresses; border mask applied at convert) and converted mid-stage after
// kf=0's 12 MFMAs, so vmcnt waits are covered by MFMA issue.
template<int R, int CPT, int COTN, bool BN>
__global__ __launch_bounds__(256, 2) void conv_mfma_kernel(
    const float* __restrict__ in, const uint4* __restrict__ Wh, const uint4* __restrict__ Wl,
    const float* __restrict__ s1, const float* __restrict__ t1, float* __restrict__ out)
{
  // [buf][kf][hilo][chunk of 2048 halves = frag (c32|p32)*512 + lam*8 + j]
  __shared__ _Float16 Abuf[2][2][2][2048];
  __shared__ _Float16 Bbuf[2][2][2][2048];
  const int t = threadIdx.x;
  const int lam = t & 63;
  const int g = t >> 6;          // wave id = c32 group (A stage) = p32 group (B stage)

  int n, pt_blk, cot;
  if (COTN == 2){
    int xcd = blockIdx.x & 7;
    int rest = blockIdx.x >> 3;  // 0..143
    n = xcd * 4 + rest / 36;
    int inner = rest % 36;
    pt_blk = inner % 18;
    cot = inner / 18;
  } else {
    pt_blk = blockIdx.x % 18;
    cot = 0;
    n = blockIdx.x / 18;
  }
  const int pbase = pt_blk * 128;
  const int cobase = cot * 128;

  const int khi = lam >> 5;                    // k-half of fragment
  const int pp = (g << 5) + (lam & 31);
  const int p = pbase + pp;
  const int ph = p / 48, pw = p - ph * 48;
  const float* in_n = in + (size_t)n * CPT * P2304;

  const int S = (R * CPT) / 32;                // BK=32 stages
  const int KTPT = CPT / 16;                   // 16-chunks per tap

  f32x16 acc_hh[2][2], acc_x[2][2];
#pragma unroll
  for (int a = 0; a < 2; ++a)
#pragma unroll
    for (int b = 0; b < 2; ++b){
#pragma unroll
      for (int e = 0; e < 16; ++e){ acc_hh[a][b][e] = 0.f; acc_x[a][b][e] = 0.f; }
    }

  // prefetch state
  uint4 rAh[2], rAl[2];
  float rB[16];
  bool vmask;

  // issue global loads for stage SV (A frags for c32=g, B 16 floats), no waits
#define ISSUE(SV)                                                             \
  {                                                                           \
    int s_ = (SV);                                                            \
    _Pragma("unroll")                                                         \
    for (int kf = 0; kf < 2; ++kf){                                           \
      int fi = (((2 * s_ + kf) * COTN + cot) * 4 + g) * 64 + lam;             \
      rAh[kf] = Wh[fi];                                                       \
      rAl[kf] = Wl[fi];                                                       \
    }                                                                         \
    int r_ = (R == 1) ? 0 : ((2 * s_) / KTPT);                                \
    int cbase_ = ((2 * s_) % KTPT) * 16;                                      \
    int dh_ = (R == 1) ? 0 : (r_ / 3 - 1);                                    \
    int dw_ = (R == 1) ? 0 : (r_ - (r_ / 3) * 3 - 1);                         \
    int hh_ = ph + dh_, ww_ = pw + dw_;                                       \
    vmask = ((unsigned)hh_ < 48u) & ((unsigned)ww_ < 48u);                    \
    int hc_ = min(max(hh_, 0), 47), wc_ = min(max(ww_, 0), 47);               \
    const float* src_ = in_n + hc_ * 48 + wc_                                 \
                        + (size_t)(cbase_ + khi * 8) * P2304;                 \
    _Pragma("unroll")                                                         \
    for (int kf = 0; kf < 2; ++kf)                                            \
      _Pragma("unroll")                                                       \
      for (int j = 0; j < 8; ++j)                                             \
        rB[kf * 8 + j] = src_[(kf * 16 + j) * P2304];                         \
  }

  // convert prefetched data and write to LDS buffer NXT (vmcnt waits here)
#define STASH(NXT)                                                            \
  {                                                                           \
    _Pragma("unroll")                                                         \
    for (int kf = 0; kf < 2; ++kf){                                           \
      *(uint4*)&Abuf[NXT][kf][0][t * 8] = rAh[kf];                            \
      *(uint4*)&Abuf[NXT][kf][1][t * 8] = rAl[kf];                            \
      half8 vh, vl;                                                           \
      _Pragma("unroll")                                                       \
      for (int j = 0; j < 8; ++j){                                            \
        float v = vmask ? rB[kf * 8 + j] : 0.0f;                              \
        _Float16 h = (_Float16)v;                                             \
        vh[j] = h;                                                            \
        vl[j] = (_Float16)((v - (float)h) * 2048.0f);                         \
      }                                                                       \
      *(half8*)&Bbuf[NXT][kf][0][t * 8] = vh;                                 \
      *(half8*)&Bbuf[NXT][kf][1][t * 8] = vl;                                 \
    }                                                                         \
  }

  // 12 MFMAs on buffer CUR, k-fragment KF
#define COMPUTE(CUR, KF)                                                      \
  {                                                                           \
    const int ct0 = (g & 1) * 2, pt0 = (g >> 1) * 2;                          \
    half8 fAh[2], fAl[2], fBh[2], fBl[2];                                     \
    _Pragma("unroll")                                                         \
    for (int a = 0; a < 2; ++a){                                              \
      fAh[a] = *(half8*)&Abuf[CUR][KF][0][(ct0 + a) * 512 + lam * 8];         \
      fAl[a] = *(half8*)&Abuf[CUR][KF][1][(ct0 + a) * 512 + lam * 8];         \
      fBh[a] = *(half8*)&Bbuf[CUR][KF][0][(pt0 + a) * 512 + lam * 8];         \
      fBl[a] = *(half8*)&Bbuf[CUR][KF][1][(pt0 + a) * 512 + lam * 8];         \
    }                                                                         \
    _Pragma("unroll")                                                         \
    for (int a = 0; a < 2; ++a)                                               \
      _Pragma("unroll")                                                       \
      for (int b = 0; b < 2; ++b){                                            \
        acc_hh[a][b] = __builtin_amdgcn_mfma_f32_32x32x16_f16(                \
            fAh[a], fBh[b], acc_hh[a][b], 0, 0, 0);                           \
        acc_x[a][b] = __builtin_amdgcn_mfma_f32_32x32x16_f16(                 \
            fAh[a], fBl[b], acc_x[a][b], 0, 0, 0);                            \
        acc_x[a][b] = __builtin_amdgcn_mfma_f32_32x32x16_f16(                 \
            fAl[a], fBh[b], acc_x[a][b], 0, 0, 0);                            \
      }                                                                       \
  }

  // prologue: fill buffer 0 with stage 0
  ISSUE(0);
  STASH(0);
  __syncthreads();

  for (int s = 0; s < S; ++s){
    const int cur = s & 1, nxt = cur ^ 1;
    const bool more = (s + 1 < S);
    if (more) ISSUE(s + 1);
    COMPUTE(cur, 0);
    if (more) STASH(nxt);
    COMPUTE(cur, 1);
    __syncthreads();
  }
#undef ISSUE
#undef STASH
#undef COMPUTE

  // epilogue: combine hi/lo passes, optional bn+leaky, store f32
  const int M = COTN * 128;
#pragma unroll
  for (int a = 0; a < 2; ++a){
    const int ctile = (g & 1) * 2 + a;
#pragma unroll
    for (int b = 0; b < 2; ++b){
      const int ptile = (g >> 1) * 2 + b;
      const int pg = pbase + ptile * 32 + (lam & 31);
#pragma unroll
      for (int rg = 0; rg < 16; ++rg){
        const int row = (rg & 3) + 8 * (rg >> 2) + 4 * (lam >> 5);
        const int co = cobase + ctile * 32 + row;
        float val = acc_hh[a][b][rg] + acc_x[a][b][rg] * (1.0f / 2048.0f);
        if (BN){
          val = val * s1[co] + t1[co];
          val = val > 0.f ? val : 0.01f * val;
        }
        out[((size_t)n * M + co) * P2304 + pg] = val;
      }
    }
  }
}

// ---------------- x_ave (mean over 2304 positions per (n,c)) ----------------
__global__ void xave_kernel(const float* __restrict__ x2, float* __restrict__ xave){
  __shared__ float red[4];
  int nc = blockIdx.x, t = threadIdx.x;
  const float* row = x2 + nc * P2304;
  float s = 0.f;
#pragma unroll
  for (int i = 0; i < 9; i++) s += row[t + 256 * i];
  float w = wredSum(s);
  if ((t & 63) == 0) red[t >> 6] = w;
  __syncthreads();
  if (t == 0) xave[nc] = (red[0] + red[1] + red[2] + red[3]) * (1.0f / 2304.0f);
}

// l2-normalize x_ave over channels
__global__ void xan_kernel(const float* __restrict__ xave, float* __restrict__ xan){
  __shared__ float red[2];
  int n = blockIdx.x, t = threadIdx.x; // 128 threads
  float v = xave[n * 128 + t];
  float w = wredSum(v * v);
  if ((t & 63) == 0) red[t >> 6] = w;
  __syncthreads();
  float norm = fmaxf(sqrtf(red[0] + red[1]), 1e-12f);
  xan[n * 128 + t] = v / norm;
}

// cos[n,p] = <xan, x2hat[:,p]>
__global__ void cos_kernel(const float* __restrict__ x2, const float* __restrict__ xan,
                           float* __restrict__ cosb){
  int idx = blockIdx.x * 256 + threadIdx.x;
  if (idx >= N_IMG * P2304) return;
  int n = idx / P2304;
  int p = idx - n * P2304;
  const float* xp = x2 + n * C2 * P2304 + p;
  const float* an = xan + n * 128;
  float dot = 0.f, ss = 0.f;
  for (int c = 0; c < 128; c++){
    float v = xp[c * P2304];
    dot += an[c] * v;
    ss  += v * v;
  }
  cosb[idx] = dot / fmaxf(sqrtf(ss), 1e-12f);
}

// ---------------- LBP code + normalization + qlv ----------------
__global__ void lbp_kernel(const float* __restrict__ cosb, float* __restrict__ code,
                           float* __restrict__ qlv){
  __shared__ float red[4];
  int n = blockIdx.x;
  int l = threadIdx.x;           // 256 positions, l = ir*16+ic
  int ir = l >> 4, ic = l & 15;
  const float* cn = cosb + n * P2304;
  float cs4 = cn[(16 + ir) * 48 + (16 + ic)];
  const float wts[9] = {1.f, 2.f, 4.f, 8.f, 0.f, 16.f, 32.f, 64.f, 128.f};
  float codev = 0.f;
#pragma unroll
  for (int j = 0; j < 9; j++){
    int jr = j / 3, jc = j - 3 * (j / 3);
    float vv = cn[(jr * 16 + ir) * 48 + (jc * 16 + ic)];
    if (vv > cs4) codev += wts[j];
  }
  float w;
  w = wredMin(codev);
  if ((l & 63) == 0) red[l >> 6] = w;
  __syncthreads();
  float mn = fminf(fminf(red[0], red[1]), fminf(red[2], red[3]));
  __syncthreads();
  w = wredMax(codev);
  if ((l & 63) == 0) red[l >> 6] = w;
  __syncthreads();
  float mx = fmaxf(fmaxf(red[0], red[1]), fmaxf(red[2], red[3]));
  __syncthreads();
  float cd = (codev - mn) / (mx - mn);
  w = wredMin(cd);
  if ((l & 63) == 0) red[l >> 6] = w;
  __syncthreads();
  float cmin = fminf(fminf(red[0], red[1]), fminf(red[2], red[3]));
  __syncthreads();
  w = wredMax(cd);
  if ((l & 63) == 0) red[l >> 6] = w;
  __syncthreads();
  float cmax = fmaxf(fmaxf(red[0], red[1]), fmaxf(red[2], red[3]));
  code[n * 256 + l] = cd;
  if (l < 128){
    float tmp = (float)(2 * l + 1) * (1.0f / 256.0f);
    qlv[n * 128 + l] = tmp * (cmax - cmin) + cmin;
  }
}

// quantT[n][lev][p] = thresholded soft-assignment (transposed for coalescing)
__global__ void quant_kernel(const float* __restrict__ code, const float* __restrict__ qlv,
                             float* __restrict__ quantT){
  __shared__ float cs[256];
  __shared__ float qs[128];
  int n = blockIdx.x, t = threadIdx.x;
  cs[t] = code[n * 256 + t];
  if (t < 128) qs[t] = qlv[n * 128 + t];
  __syncthreads();
  float thr = 1.0f - (qs[1] - qs[0]);
  float* dst = quantT + n * LEV * 256;
#pragma unroll 4
  for (int i = 0; i < 128; i++){
    int v = t + 256 * i;
    int lv = v >> 8;
    int p = v & 255;
    float qq = 1.0f - fabsf(qs[lv] - cs[p]);
    dst[v] = (qq > thr) ? qq : 0.f;
  }
}

// sta[n][i] = sum_p quant / total
__global__ void sta_kernel(const float* __restrict__ quantT, float* __restrict__ sta){
  __shared__ float red[2];
  int n = blockIdx.x, i = threadIdx.x; // 128 threads
  const float* qr = quantT + (n * LEV + i) * 256;
  float s = 0.f;
  for (int p = 0; p < 256; p++) s += qr[p];
  float w = wredSum(s);
  if ((i & 63) == 0) red[i >> 6] = w;
  __syncthreads();
  float tot = red[0] + red[1];
  sta[n * 128 + i] = s / tot;
}

// h1 = leaky(f1_w @ [qlv; sta])
__global__ void h1_kernel(const float* __restrict__ f1w, const float* __restrict__ qlv,
                          const float* __restrict__ sta, float* __restrict__ h1){
  int idx = blockIdx.x * 256 + threadIdx.x;
  if (idx >= N_IMG * 64 * 128) return;
  int l = idx & 127;
  int n = idx >> 13;
  int o = (idx >> 7) & 63;
  float a = f1w[o * 2] * qlv[n * 128 + l] + f1w[o * 2 + 1] * sta[n * 128 + l];
  h1[idx] = a > 0.f ? a : 0.01f * a;
}

// generic per-image "W @ B" with optional bn+relu: C[n,o,l] = act(sum_c Wm[o,c]*B[n,c,l])
__global__ void gemm_w_kernel(const float* __restrict__ Wm, const float* __restrict__ B,
                              float* __restrict__ Cout, int Cdim, int O, int total, int mode,
                              const float* __restrict__ g, const float* __restrict__ bb,
                              const float* __restrict__ mm, const float* __restrict__ vv){
  int idx = blockIdx.x * 256 + threadIdx.x;
  if (idx >= total) return;
  int per_n = (O >> 2) << 7;
  int n = idx / per_n;
  int rem = idx - n * per_n;
  int o0 = (rem >> 7) << 2;
  int l = rem & 127;
  const float* Bn = B + (n * Cdim) * 128 + l;
  const float* w0 = Wm + (o0 + 0) * Cdim;
  const float* w1 = Wm + (o0 + 1) * Cdim;
  const float* w2 = Wm + (o0 + 2) * Cdim;
  const float* w3 = Wm + (o0 + 3) * Cdim;
  float a0 = 0, a1 = 0, a2 = 0, a3 = 0;
  for (int c = 0; c < Cdim; c++){
    float bv = Bn[c * 128];
    a0 += w0[c] * bv; a1 += w1[c] * bv; a2 += w2[c] * bv; a3 += w3[c] * bv;
  }
  float av[4] = {a0, a1, a2, a3};
#pragma unroll
  for (int j = 0; j < 4; j++){
    int o = o0 + j;
    float val = av[j];
    if (mode == 1){
      float s = g[o] * (1.0f / sqrtf(vv[o] + 1e-5f));
      val = (val - mm[o]) * s + bb[o];
      val = fmaxf(val, 0.f);
    }
    Cout[(n * O + o) * 128 + l] = val;
  }
}

// s = concat([h2, broadcast(x_ave)], channel dim)
__global__ void concat_kernel(const float* __restrict__ h2, const float* __restrict__ xave,
                              float* __restrict__ s){
  int idx = blockIdx.x * 256 + threadIdx.x;
  if (idx >= N_IMG * 256 * 128) return;
  int l = idx & 127;
  int c = (idx >> 7) & 255;
  int n = idx >> 15;
  s[idx] = (c < 128) ? h2[(n * 128 + c) * 128 + l] : xave[n * 128 + (c - 128)];
}

// sc[n,l,m] = sum_c k[n,c,l]*q[n,c,m]
__global__ void attn_sc_kernel(const float* __restrict__ k, const float* __restrict__ q,
                               float* __restrict__ sc){
  int idx = blockIdx.x * 256 + threadIdx.x;
  if (idx >= N_IMG * 32 * 128) return;
  int m = idx & 127;
  int l0 = ((idx >> 7) & 31) << 2;
  int n = idx >> 12;
  const float* kn = k + n * 256 * 128;
  const float* qn = q + n * 256 * 128 + m;
  float a0 = 0, a1 = 0, a2 = 0, a3 = 0;
  for (int c = 0; c < 256; c++){
    float qv = qn[c * 128];
    const float* kr = kn + c * 128 + l0;
    a0 += kr[0] * qv; a1 += kr[1] * qv; a2 += kr[2] * qv; a3 += kr[3] * qv;
  }
  float* dst = sc + (n * 128 + l0) * 128 + m;
  dst[0] = a0; dst[128] = a1; dst[256] = a2; dst[384] = a3;
}

__global__ void softmax_kernel(float* __restrict__ sc){
  __shared__ float red[2];
  int row = blockIdx.x;
  int t = threadIdx.x; // 128
  float v = sc[row * 128 + t];
  float w = wredMax(v);
  if ((t & 63) == 0) red[t >> 6] = w;
  __syncthreads();
  float mx = fmaxf(red[0], red[1]);
  float e = expf(v - mx);
  float s = wredSum(e);
  __syncthreads();
  if ((t & 63) == 0) red[t >> 6] = s;
  __syncthreads();
  sc[row * 128 + t] = e / (red[0] + red[1]);
}

__global__ void transpose_sc_kernel(const float* __restrict__ sc, float* __restrict__ scT){
  int idx = blockIdx.x * 256 + threadIdx.x;
  if (idx >= N_IMG * 128 * 128) return;
  int l = idx & 127;
  int m = (idx >> 7) & 127;
  int n = idx >> 14;
  scT[idx] = sc[(n * 128 + l) * 128 + m];
}

// f[n,c,l] = sum_m v[n,c,m]*scT[n,m,l]
__global__ void attn_f_kernel(const float* __restrict__ vb, const float* __restrict__ scT,
                              float* __restrict__ f){
  int idx = blockIdx.x * 256 + threadIdx.x;
  if (idx >= N_IMG * 64 * 128) return;
  int l = idx & 127;
  int c0 = ((idx >> 7) & 63) << 2;
  int n = idx >> 13;
  const float* vn = vb + (n * 256 + c0) * 128;
  const float* sn = scT + n * 128 * 128 + l;
  float a0 = 0, a1 = 0, a2 = 0, a3 = 0;
  for (int m = 0; m < 128; m++){
    float sv = sn[m * 128];
    a0 += vn[m] * sv; a1 += vn[128 + m] * sv; a2 += vn[256 + m] * sv; a3 += vn[384 + m] * sv;
  }
  float* dst = f + (n * 256 + c0) * 128 + l;
  dst[0] = a0; dst[128] = a1; dst[256] = a2; dst[384] = a3;
}

// outs[n,c,p] = sum_lev g[n,c,lev]*quantT[n,lev,p]
__global__ void final_kernel(const float* __restrict__ g, const float* __restrict__ quantT,
                             float* __restrict__ outs){
  int idx = blockIdx.x * 256 + threadIdx.x;
  if (idx >= N_IMG * 64 * 256) return;
  int p = idx & 255;
  int c0 = ((idx >> 8) & 63) << 2;
  int n = idx >> 14;
  const float* gn = g + (n * 256 + c0) * 128;
  const float* qn = quantT + (n * LEV) * 256 + p;
  float a0 = 0, a1 = 0, a2 = 0, a3 = 0;
  for (int lv = 0; lv < 128; lv++){
    float qv = qn[lv * 256];
    a0 += gn[lv] * qv; a1 += gn[128 + lv] * qv; a2 += gn[256 + lv] * qv; a3 += gn[384 + lv] * qv;
  }
  float* dst = outs + (n * 256 + c0) * 256 + p;
  dst[0] = a0; dst[256] = a1; dst[512] = a2; dst[768] = a3;
}

// bilinear 16x16 -> 48x48 (align_corners-style linspace(0,15,48))
__global__ void resize_kernel(const float* __restrict__ outs, float* __restrict__ dout){
  int idx = blockIdx.x * 256 + threadIdx.x;
  if (idx >= N_IMG * 256 * P2304) return;
  int ow = idx % 48;
  int tmp = idx / 48;
  int oh = tmp % 48;
  int nc = tmp / 48;
  const float* src = outs + nc * 256;
  float fy = oh * (15.0f / 47.0f);
  float fx = ow * (15.0f / 47.0f);
  int y0 = (int)fy;
  int x0 = (int)fx;
  int y1 = min(y0 + 1, 15);
  int x1 = min(x0 + 1, 15);
  float wy = fy - (float)y0;
  float wx = fx - (float)x0;
  float v00 = src[y0 * 16 + x0], v01 = src[y0 * 16 + x1];
  float v10 = src[y1 * 16 + x0], v11 = src[y1 * 16 + x1];
  dout[idx] = v00 * (1.f - wy) * (1.f - wx) + v01 * (1.f - wy) * wx
            + v10 * wy * (1.f - wx) + v11 * wy * wx;
}

// ---------------- launcher ----------------
extern "C" void kernel_launch(void* const* d_in, const int* in_sizes, int n_in,
                              void* d_out, int out_size, void* d_ws, size_t ws_size,
                              hipStream_t stream)
{
  const float* x       = (const float*)d_in[0];
  const float* conv1_w = (const float*)d_in[1];
  const float* bn1_g   = (const float*)d_in[2];
  const float* bn1_b   = (const float*)d_in[3];
  const float* bn1_m   = (const float*)d_in[4];
  const float* bn1_v   = (const float*)d_in[5];
  const float* conv2_w = (const float*)d_in[6];
  const float* f1_w    = (const float*)d_in[7];
  const float* f2_w    = (const float*)d_in[8];
  const float* f2_g    = (const float*)d_in[9];
  const float* f2_b    = (const float*)d_in[10];
  const float* f2_m    = (const float*)d_in[11];
  const float* f2_v    = (const float*)d_in[12];
  const float* out1_w  = (const float*)d_in[13];
  const float* out1_g  = (const float*)d_in[14];
  const float* out1_b  = (const float*)d_in[15];
  const float* out1_m  = (const float*)d_in[16];
  const float* out1_v  = (const float*)d_in[17];
  const float* k_w     = (const float*)d_in[18];
  const float* q_w     = (const float*)d_in[19];
  const float* v_w     = (const float*)d_in[20];
  const float* out_w   = (const float*)d_in[21];
  const float* out_g   = (const float*)d_in[22];
  const float* out_b   = (const float*)d_in[23];
  const float* out_m   = (const float*)d_in[24];
  const float* out_v   = (const float*)d_in[25];

  float* ws = (float*)d_ws;
  float* dout = (float*)d_out;

  // large buffers
  float* w_y   = ws;                  // 18874368 f (y: 32x256x2304) -- dead after conv2
  float* w_x2  = ws + 18874368;       // 9437184 f
  float* w_W1h = ws + 28311552;       // 589824 f-slots = 1179648 f16 (packed frags)
  float* w_W1l = ws + 28901376;       // 589824
  float* w_W2h = ws + 29491200;       // 16384 f-slots = 32768 f16
  float* w_W2l = ws + 29507584;       // 16384
  float* w_s1  = ws + 29523968;       // 256
  float* w_t1  = ws + 29524224;       // 256  => total 29524480 f = 118.1 MB
  // small buffers reuse the y region (only written after conv2 consumed y)
  float* w_xave = w_y + 0;            // 4096
  float* w_xan  = w_y + 4096;         // 4096
  float* w_cos  = w_y + 8192;         // 73728
  float* w_code = w_y + 81920;        // 8192
  float* w_qlv  = w_y + 90112;        // 4096
  float* w_sta  = w_y + 94208;        // 4096
  float* w_quant= w_y + 98304;        // 1048576 (quantT [n][lev][p])
  float* w_h1   = w_y + 1146880;      // 262144
  float* w_h2   = w_y + 1409024;      // 524288
  float* w_s    = w_y + 1933312;      // 1048576
  float* w_k    = w_y + 2981888;      // 1048576
  float* w_q    = w_y + 4030464;      // 1048576
  float* w_v    = w_y + 5079040;      // 1048576
  float* w_sc   = w_y + 6127616;      // 524288
  float* w_scT  = w_y + 6651904;      // 524288
  float* w_f    = w_y + 7176192;      // 1048576
  float* w_g    = w_y + 8224768;      // 1048576
  float* w_outs = w_y + 9273344;      // 2097152
  float* w_s2   = w_y + 11370496;     // 1048576 (ends 12419072 < 18874368)

  prep_w1_kernel<<<576, 256, 0, stream>>>(conv1_w, (uint4*)w_W1h, (uint4*)w_W1l);
  prep_w2_kernel<<<16, 256, 0, stream>>>(conv2_w, (uint4*)w_W2h, (uint4*)w_W2l);
  prep_bn_kernel<<<1, 256, 0, stream>>>(bn1_g, bn1_b, bn1_m, bn1_v, w_s1, w_t1);

  conv_mfma_kernel<9, 512, 2, true><<<1152, 256, 0, stream>>>(
      x, (const uint4*)w_W1h, (const uint4*)w_W1l, w_s1, w_t1, w_y);
  conv_mfma_kernel<1, 256, 1, false><<<576, 256, 0, stream>>>(
      w_y, (const uint4*)w_W2h, (const uint4*)w_W2l, w_s1, w_t1, w_x2);

  xave_kernel<<<4096, 256, 0, stream>>>(w_x2, w_xave);
  xan_kernel<<<32, 128, 0, stream>>>(w_xave, w_xan);
  cos_kernel<<<288, 256, 0, stream>>>(w_x2, w_xan, w_cos);
  lbp_kernel<<<32, 256, 0, stream>>>(w_cos, w_code, w_qlv);
  quant_kernel<<<32, 256, 0, stream>>>(w_code, w_qlv, w_quant);
  sta_kernel<<<32, 128, 0, stream>>>(w_quant, w_sta);
  h1_kernel<<<1024, 256, 0, stream>>>(f1_w, w_qlv, w_sta, w_h1);
  gemm_w_kernel<<<512, 256, 0, stream>>>(f2_w, w_h1, w_h2, 64, 128, N_IMG * 32 * 128, 1,
                                         f2_g, f2_b, f2_m, f2_v);
  concat_kernel<<<4096, 256, 0, stream>>>(w_h2, w_xave, w_s);
  gemm_w_kernel<<<1024, 256, 0, stream>>>(out1_w, w_s, w_s2, 256, 256, N_IMG * 64 * 128, 1,
                                          out1_g, out1_b, out1_m, out1_v);
  gemm_w_kernel<<<1024, 256, 0, stream>>>(k_w, w_s2, w_k, 256, 256, N_IMG * 64 * 128, 0,
                                          nullptr, nullptr, nullptr, nullptr);
  gemm_w_kernel<<<1024, 256, 0, stream>>>(q_w, w_s2, w_q, 256, 256, N_IMG * 64 * 128, 0,
                                          nullptr, nullptr, nullptr, nullptr);
  gemm_w_kernel<<<1024, 256, 0, stream>>>(v_w, w_s2, w_v, 256, 256, N_IMG * 64 * 128, 0,
                                          nullptr, nullptr, nullptr, nullptr);
  attn_sc_kernel<<<512, 256, 0, stream>>>(w_k, w_q, w_sc);
  softmax_kernel<<<4096, 128, 0, stream>>>(w_sc);
  transpose_sc_kernel<<<2048, 256, 0, stream>>>(w_sc, w_scT);
  attn_f_kernel<<<1024, 256, 0, stream>>>(w_v, w_scT, w_f);
  gemm_w_kernel<<<1024, 256, 0, stream>>>(out_w, w_f, w_g, 256, 256, N_IMG * 64 * 128, 1,
                                          out_g, out_b, out_m, out_v);
  final_kernel<<<2048, 256, 0, stream>>>(w_g, w_quant, w_outs);
  resize_kernel<<<73728, 256, 0, stream>>>(w_outs, dout);
}